// Round 5
// baseline (833.101 us; speedup 1.0000x reference)
//
#include <hip/hip_runtime.h>
#include <hip/hip_bf16.h>
#include <stdint.h>

#define BB 2
#define SS 192
#define DD 256
#define NROW (BB * SS)   // 384
#define NE (NROW * DD)   // 98304

// ---------------- threefry2x32-20 (Random123 / JAX, partitionable) ----------------
__device__ __forceinline__ uint32_t rotl32(uint32_t v, int d) {
  return (v << d) | (v >> (32 - d));
}

__device__ inline void threefry2x32(uint32_t k0, uint32_t k1, uint32_t x0, uint32_t x1,
                                    uint32_t* o0, uint32_t* o1) {
  uint32_t ks2 = k0 ^ k1 ^ 0x1BD11BDAu;
  x0 += k0; x1 += k1;
  const int ra[4] = {13, 15, 26, 6};
  const int rb[4] = {17, 29, 16, 24};
#pragma unroll
  for (int i = 0; i < 4; i++) { x0 += x1; x1 = rotl32(x1, ra[i]); x1 ^= x0; }
  x0 += k1; x1 += ks2 + 1u;
#pragma unroll
  for (int i = 0; i < 4; i++) { x0 += x1; x1 = rotl32(x1, rb[i]); x1 ^= x0; }
  x0 += ks2; x1 += k0 + 2u;
#pragma unroll
  for (int i = 0; i < 4; i++) { x0 += x1; x1 = rotl32(x1, ra[i]); x1 ^= x0; }
  x0 += k0; x1 += k1 + 3u;
#pragma unroll
  for (int i = 0; i < 4; i++) { x0 += x1; x1 = rotl32(x1, rb[i]); x1 ^= x0; }
  x0 += k1; x1 += ks2 + 4u;
#pragma unroll
  for (int i = 0; i < 4; i++) { x0 += x1; x1 = rotl32(x1, ra[i]); x1 ^= x0; }
  x0 += ks2; x1 += k0 + 5u;
  *o0 = x0; *o1 = x1;
}

__device__ inline float erfinv_xla_f32(float x) {
  float w = -log1pf(-x * x);
  float p;
  if (w < 5.0f) {
    w = w - 2.5f;
    p = 2.81022636e-08f;
    p = 3.43273939e-07f + p * w;
    p = -3.5233877e-06f + p * w;
    p = -4.39150654e-06f + p * w;
    p = 0.00021858087f + p * w;
    p = -0.00125372503f + p * w;
    p = -0.00417768164f + p * w;
    p = 0.246640727f + p * w;
    p = 1.50140941f + p * w;
  } else {
    w = sqrtf(w) - 3.0f;
    p = -0.000200214257f;
    p = 0.000100950558f + p * w;
    p = 0.00134934322f + p * w;
    p = -0.00367342844f + p * w;
    p = 0.00573950773f + p * w;
    p = -0.0076224613f + p * w;
    p = 0.00943887047f + p * w;
    p = 1.00167406f + p * w;
    p = 2.83297682f + p * w;
  }
  return p * x;
}

__device__ inline float jax_normal_from_bits(uint32_t bits) {
  float f = __uint_as_float((bits >> 9) | 0x3f800000u) - 1.0f;
  const float lo = -0.99999994f;  // nextafter(-1, 0)
  float u = f * (1.0f - lo) + lo;
  u = fmaxf(lo, u);
  return 1.4142135623730951f * erfinv_xla_f32(u);
}

__device__ inline float jax_normal_at(uint32_t ka, uint32_t kb, uint32_t i) {
  uint32_t o0, o1;
  threefry2x32(ka, kb, 0u, i, &o0, &o1);
  return jax_normal_from_bits(o0 ^ o1);
}

// ---------------- reductions (256 threads = 4 waves of 64) ----------------
__device__ inline double blockSum(double v, double* red, int tid) {
#pragma unroll
  for (int o = 32; o > 0; o >>= 1) v += __shfl_down(v, o, 64);
  __syncthreads();
  if ((tid & 63) == 0) red[tid >> 6] = v;
  __syncthreads();
  return (red[0] + red[1]) + (red[2] + red[3]);
}

__device__ inline double reduceS_sum(const double* arr, double* red, int tid) {
  __syncthreads();
  if (tid < 64) {
    double v = arr[tid] + arr[tid + 64] + arr[tid + 128];
#pragma unroll
    for (int o = 32; o > 0; o >>= 1) v += __shfl_down(v, o, 64);
    if (tid == 0) red[4] = v;
  }
  __syncthreads();
  return red[4];
}

__device__ inline double reduceS_min(const double* arr, double* red, int tid) {
  __syncthreads();
  if (tid < 64) {
    double v = fmin(arr[tid], fmin(arr[tid + 64], arr[tid + 128]));
#pragma unroll
    for (int o = 32; o > 0; o >>= 1) v = fmin(v, __shfl_down(v, o, 64));
    if (tid == 0) red[5] = v;
  }
  __syncthreads();
  return red[5];
}

// ============ pipelined dot kernels (named regs only, 2-set ping-pong) ============

// ---- sdot2: per-s dot over d, float2-packed khT2, LDS vec read as double2 ----
#define SD_DEC(s) float2 s##0,s##1,s##2,s##3,s##4,s##5,s##6,s##7,s##8,s##9,s##10,s##11,s##12,s##13,s##14,s##15;
#define SD_LD(s, d0) \
  s##0=cb[((d0)+0)*SS];   s##1=cb[((d0)+1)*SS];   s##2=cb[((d0)+2)*SS];   s##3=cb[((d0)+3)*SS];  \
  s##4=cb[((d0)+4)*SS];   s##5=cb[((d0)+5)*SS];   s##6=cb[((d0)+6)*SS];   s##7=cb[((d0)+7)*SS];  \
  s##8=cb[((d0)+8)*SS];   s##9=cb[((d0)+9)*SS];   s##10=cb[((d0)+10)*SS]; s##11=cb[((d0)+11)*SS];\
  s##12=cb[((d0)+12)*SS]; s##13=cb[((d0)+13)*SS]; s##14=cb[((d0)+14)*SS]; s##15=cb[((d0)+15)*SS];
#define SD_F1(s, u, d0, acc) { double2 v_ = vp[(d0)+(u)]; acc += v_.x*(double)s##u.x; acc += v_.y*(double)s##u.y; }
#define SD_FMA(s, d0) \
  SD_F1(s,0,d0,A0)  SD_F1(s,1,d0,A1)  SD_F1(s,2,d0,A2)  SD_F1(s,3,d0,A3)  \
  SD_F1(s,4,d0,A4)  SD_F1(s,5,d0,A5)  SD_F1(s,6,d0,A6)  SD_F1(s,7,d0,A7)  \
  SD_F1(s,8,d0,A0)  SD_F1(s,9,d0,A1)  SD_F1(s,10,d0,A2) SD_F1(s,11,d0,A3) \
  SD_F1(s,12,d0,A4) SD_F1(s,13,d0,A5) SD_F1(s,14,d0,A6) SD_F1(s,15,d0,A7)

__device__ inline double sdot2(const double* __restrict__ vec, const float2* __restrict__ cb) {
  const double2* vp = (const double2*)vec;
  double A0=0,A1=0,A2=0,A3=0,A4=0,A5=0,A6=0,A7=0;
  SD_DEC(cA) SD_DEC(cB)
  SD_LD(cA, 0)
  SD_LD(cB, 16)
#pragma unroll
  for (int g = 0; g < 3; ++g) {
    SD_FMA(cA, 32*g)      SD_LD(cA, 32*g+32)
    SD_FMA(cB, 32*g+16)   SD_LD(cB, 32*g+48)
  }
  SD_FMA(cA, 96)
  SD_FMA(cB, 112)
  return ((A0+A1)+(A2+A3))+((A4+A5)+(A6+A7));
}

// ---- dsum16: d-mapped weighted sum over s, w from LDS as double2 ----
#define DS_DEC(s) float s##0,s##1,s##2,s##3,s##4,s##5,s##6,s##7,s##8,s##9,s##10,s##11,s##12,s##13,s##14,s##15;
#define DS_LD(s, s0) \
  s##0=mb[((s0)+0)*DD];   s##1=mb[((s0)+1)*DD];   s##2=mb[((s0)+2)*DD];   s##3=mb[((s0)+3)*DD];  \
  s##4=mb[((s0)+4)*DD];   s##5=mb[((s0)+5)*DD];   s##6=mb[((s0)+6)*DD];   s##7=mb[((s0)+7)*DD];  \
  s##8=mb[((s0)+8)*DD];   s##9=mb[((s0)+9)*DD];   s##10=mb[((s0)+10)*DD]; s##11=mb[((s0)+11)*DD];\
  s##12=mb[((s0)+12)*DD]; s##13=mb[((s0)+13)*DD]; s##14=mb[((s0)+14)*DD]; s##15=mb[((s0)+15)*DD];
#define DS_FMA(s, s0) { \
  const double2* wp_ = (const double2*)w + ((s0)>>1); \
  { double2 w_=wp_[0]; A0+=w_.x*(double)s##0;  A1+=w_.y*(double)s##1; }  \
  { double2 w_=wp_[1]; A2+=w_.x*(double)s##2;  A3+=w_.y*(double)s##3; }  \
  { double2 w_=wp_[2]; A4+=w_.x*(double)s##4;  A5+=w_.y*(double)s##5; }  \
  { double2 w_=wp_[3]; A6+=w_.x*(double)s##6;  A7+=w_.y*(double)s##7; }  \
  { double2 w_=wp_[4]; A0+=w_.x*(double)s##8;  A1+=w_.y*(double)s##9; }  \
  { double2 w_=wp_[5]; A2+=w_.x*(double)s##10; A3+=w_.y*(double)s##11; } \
  { double2 w_=wp_[6]; A4+=w_.x*(double)s##12; A5+=w_.y*(double)s##13; } \
  { double2 w_=wp_[7]; A6+=w_.x*(double)s##14; A7+=w_.y*(double)s##15; } }

__device__ inline double dsum16(const double* __restrict__ w, const float* __restrict__ mb) {
  double A0=0,A1=0,A2=0,A3=0,A4=0,A5=0,A6=0,A7=0;
  DS_DEC(cA) DS_DEC(cB)
  DS_LD(cA, 0)
  DS_LD(cB, 16)
#pragma unroll
  for (int g = 0; g < 5; ++g) {
    DS_FMA(cA, 32*g)      DS_LD(cA, 32*g+32)
    DS_FMA(cB, 32*g+16)   DS_LD(cB, 32*g+48)
  }
  DS_FMA(cA, 160)
  DS_FMA(cB, 176)
  return ((A0+A1)+(A2+A3))+((A4+A5)+(A6+A7));
}

// ---- hmu8: fused h = w.v, mu = w.k ----
#define HM_DEC(s) float s##v0,s##v1,s##v2,s##v3,s##v4,s##v5,s##v6,s##v7, \
                        s##k0,s##k1,s##k2,s##k3,s##k4,s##k5,s##k6,s##k7;
#define HM_LD(s, s0) \
  s##v0=vbp[((s0)+0)*DD]; s##v1=vbp[((s0)+1)*DD]; s##v2=vbp[((s0)+2)*DD]; s##v3=vbp[((s0)+3)*DD]; \
  s##v4=vbp[((s0)+4)*DD]; s##v5=vbp[((s0)+5)*DD]; s##v6=vbp[((s0)+6)*DD]; s##v7=vbp[((s0)+7)*DD]; \
  s##k0=kbp[((s0)+0)*DD]; s##k1=kbp[((s0)+1)*DD]; s##k2=kbp[((s0)+2)*DD]; s##k3=kbp[((s0)+3)*DD]; \
  s##k4=kbp[((s0)+4)*DD]; s##k5=kbp[((s0)+5)*DD]; s##k6=kbp[((s0)+6)*DD]; s##k7=kbp[((s0)+7)*DD];
#define HM_FMA(s, s0) { \
  const double2* wp_ = (const double2*)w + ((s0)>>1); \
  { double2 w_=wp_[0]; H0+=w_.x*(double)s##v0; M0+=w_.x*(double)s##k0; H1+=w_.y*(double)s##v1; M1+=w_.y*(double)s##k1; } \
  { double2 w_=wp_[1]; H2+=w_.x*(double)s##v2; M2+=w_.x*(double)s##k2; H3+=w_.y*(double)s##v3; M3+=w_.y*(double)s##k3; } \
  { double2 w_=wp_[2]; H0+=w_.x*(double)s##v4; M0+=w_.x*(double)s##k4; H1+=w_.y*(double)s##v5; M1+=w_.y*(double)s##k5; } \
  { double2 w_=wp_[3]; H2+=w_.x*(double)s##v6; M2+=w_.x*(double)s##k6; H3+=w_.y*(double)s##v7; M3+=w_.y*(double)s##k7; } }

__device__ inline void hmu8(const double* __restrict__ w, const float* __restrict__ vbp,
                            const float* __restrict__ kbp, double& hout, double& muout) {
  double H0=0,H1=0,H2=0,H3=0,M0=0,M1=0,M2=0,M3=0;
  HM_DEC(cA) HM_DEC(cB)
  HM_LD(cA, 0)
  HM_LD(cB, 8)
#pragma unroll
  for (int g = 0; g < 11; ++g) {
    HM_FMA(cA, 16*g)     HM_LD(cA, 16*g+16)
    HM_FMA(cB, 16*g+8)   HM_LD(cB, 16*g+24)
  }
  HM_FMA(cA, 176)
  HM_FMA(cB, 184)
  hout = (H0+H1)+(H2+H3);
  muout = (M0+M1)+(M2+M3);
}

// ---- rowdot: dot of LDS f32 vector with a contiguous W row (float4 both sides) ----
#define RD_DEC(s) float4 s##0,s##1,s##2,s##3,s##4,s##5,s##6,s##7;
#define RD_LD(s, i0) \
  s##0=wp4[(i0)+0]; s##1=wp4[(i0)+1]; s##2=wp4[(i0)+2]; s##3=wp4[(i0)+3]; \
  s##4=wp4[(i0)+4]; s##5=wp4[(i0)+5]; s##6=wp4[(i0)+6]; s##7=wp4[(i0)+7];
#define RD_F1(s, u, i0, aa, ab, ac, ad) { float4 x_ = xp[(i0)+(u)]; \
  aa += (double)x_.x*(double)s##u.x; ab += (double)x_.y*(double)s##u.y; \
  ac += (double)x_.z*(double)s##u.z; ad += (double)x_.w*(double)s##u.w; }
#define RD_FMA(s, i0) \
  RD_F1(s,0,i0,A0,A1,A2,A3) RD_F1(s,1,i0,A4,A5,A6,A7) \
  RD_F1(s,2,i0,A0,A1,A2,A3) RD_F1(s,3,i0,A4,A5,A6,A7) \
  RD_F1(s,4,i0,A0,A1,A2,A3) RD_F1(s,5,i0,A4,A5,A6,A7) \
  RD_F1(s,6,i0,A0,A1,A2,A3) RD_F1(s,7,i0,A4,A5,A6,A7)

__device__ inline double rowdot(const float* __restrict__ xs, const float* __restrict__ wrow) {
  const float4* wp4 = (const float4*)wrow;
  const float4* xp = (const float4*)xs;
  double A0=0,A1=0,A2=0,A3=0,A4=0,A5=0,A6=0,A7=0;
  RD_DEC(cA) RD_DEC(cB)
  RD_LD(cA, 0)
  RD_LD(cB, 8)
#pragma unroll
  for (int g = 0; g < 3; ++g) {
    RD_FMA(cA, 16*g)      RD_LD(cA, 16*g+16)
    RD_FMA(cB, 16*g+8)    RD_LD(cB, 16*g+24)
  }
  RD_FMA(cA, 48)
  RD_FMA(cB, 56)
  return ((A0+A1)+(A2+A3))+((A4+A5)+(A6+A7));
}

// ---------------- fused QKV projection + expmap0 rows ----------------
__global__ __launch_bounds__(256) void proj_kernel(
    const float* __restrict__ q_in, const float* __restrict__ k_in, const float* __restrict__ v_in,
    const float* __restrict__ Wq, const float* __restrict__ Wk, const float* __restrict__ Wv,
    const float* __restrict__ bq, const float* __restrict__ bk, const float* __restrict__ bv,
    float* __restrict__ qh, float* __restrict__ kb, float* __restrict__ vb,
    float* __restrict__ kh, float2* __restrict__ khT2, double* __restrict__ y2g) {
  const int row = blockIdx.x, m = blockIdx.y, j = threadIdx.x;
  __shared__ __align__(16) float xs[DD];
  __shared__ double red[8];
  const float* x; const float* W; const float* bias;
  if (m == 0) { x = q_in; W = Wq; bias = bq; }
  else if (m == 1) { x = k_in; W = Wk; bias = bk; }
  else { x = v_in; W = Wv; bias = bv; }
  xs[j] = x[(size_t)row * DD + j];
  __syncthreads();
  double val = rowdot(xs, W + (size_t)j * DD) + (double)bias[j];

  if (m == 2) { vb[(size_t)row * DD + j] = (float)val; return; }

  double n2 = blockSum(val * val, red, j);
  double n = sqrt(n2);
  double cf = fmin(4.0 / (n + 1e-8), 1.0);
  double ncl = fmax(n * cf, 1e-15);
  double sc = tanh(ncl) * cf / ncl;
  if (m == 0) {
    qh[(size_t)row * DD + j] = (float)(val * sc);
  } else {
    kb[(size_t)row * DD + j] = (float)val;
    float khf = (float)(val * sc);
    kh[(size_t)row * DD + j] = khf;
    float hi = __shfl_down(khf, 1, 64);
    int bb = row / SS, s = row % SS;
    if (!(j & 1))
      khT2[((size_t)bb * (DD / 2) + (j >> 1)) * SS + s] = make_float2(khf, hi);
    double y2 = blockSum((double)khf * (double)khf, red, j);
    if (j == 0) y2g[row] = y2;
  }
}

// ---------------- main fused per-(b,q) kernel (output GEMM fused in) ----------------
__global__ __launch_bounds__(256) void resonance_main(
    const float* __restrict__ q_hyp, const float* __restrict__ k_hyp,
    const float2* __restrict__ khT2, const float* __restrict__ kmat,
    const float* __restrict__ vmat, const double* __restrict__ y2g,
    const float* __restrict__ Wo, const float* __restrict__ bo,
    const float* __restrict__ tau_p, const float* __restrict__ ts_p,
    float* __restrict__ out) {
  __shared__ __align__(16) double xq[DD], xc[DD], vr[DD];
  __shared__ __align__(16) double y2s[SS], wun[SS], wns[SS], alf[SS], bet[SS], sA[SS], sB[SS];
  __shared__ __align__(16) float hfl[DD];
  __shared__ double red[8];
  const int tid = threadIdx.x;
  const int blk = blockIdx.x;
  const int b = blk / SS;
  const size_t rowOff = (size_t)blk * DD;
  const float* khB = k_hyp + (size_t)b * SS * DD;
  const float2* khT2B = khT2 + (size_t)b * (DD / 2) * SS + tid;  // pre-offset by s=tid
  const float* kB = kmat + (size_t)b * SS * DD;
  const float* vB = vmat + (size_t)b * SS * DD;

  // inline JAX PRNG: nk = split(key(42), 3), partitionable scheme
  uint32_t nk0a, nk0b, nk1a, nk1b, nk2a, nk2b;
  threefry2x32(0u, 42u, 0u, 0u, &nk0a, &nk0b);
  threefry2x32(0u, 42u, 0u, 1u, &nk1a, &nk1b);
  threefry2x32(0u, 42u, 0u, 2u, &nk2a, &nk2b);
  const uint32_t ei = (uint32_t)(rowOff + tid);
  const double noiseval = 1e-5 * (double)jax_normal_at(nk0a, nk0b, ei);
  const double vrndval = (double)jax_normal_at(nk1a, nk1b, ei);
  const double odeval = 1e-4 * (double)jax_normal_at(nk2a, nk2b, (uint32_t)blk);

  double xqv = (double)q_hyp[rowOff + tid];
  xq[tid] = xqv;
  if (tid < SS) y2s[tid] = y2g[b * SS + tid];
  double x2q = blockSum(xqv * xqv, red, tid);  // syncs cover xq/y2s writes

  // ---- pairwise hyperbolic distance row ----
  if (tid < SS) {
    double dot = sdot2(xq, khT2B);
    double y2 = y2s[tid];
    double A = 1.0 - 2.0 * dot + y2;
    double Dn = fmax(1.0 - 2.0 * dot + x2q * y2, 1e-15);
    double Bc = 1.0 - x2q;
    double u2 = (A * A * x2q - 2.0 * A * Bc * dot + Bc * Bc * y2) / (Dn * Dn);
    double unr = sqrt(fmax(u2, 0.0));
    sA[tid] = 2.0 * atanh(fmin(unr, 1.0 - 1e-7));
  }
  double mind = reduceS_min(sA, red, tid);
  if (tid < SS) wun[tid] = exp(-(sA[tid] - mind));
  double wsum = reduceS_sum(wun, red, tid);
  if (tid < SS) wns[tid] = wun[tid] * (1.0 / (wsum + 1e-8));
  __syncthreads();

  // ---- fused: h = wns.v and mu_raw = wns.k ----
  double hreg, mu;
  hmu8(wns, vB + tid, kB + tid, hreg, mu);

  // ---- mu0 = expmap0(clip_tangent(mu)) ----
  double x2c;
  {
    double n2 = blockSum(mu * mu, red, tid);
    double n = sqrt(n2);
    double cf = fmin(4.0 / (n + 1e-8), 1.0);
    double ncl = fmax(n * cf, 1e-15);
    double th = tanh(ncl);
    xc[tid] = mu * (th * cf / ncl);
    x2c = th * th;
  }
  __syncthreads();

  // ---- Karcher flow: 3 Riemannian SGD steps ----
  for (int it = 0; it < 3; ++it) {
    if (tid < SS) {
      double dot = sdot2(xc, khT2B);
      double y2 = y2s[tid];
      double A = 1.0 - 2.0 * dot + y2;
      double Dn = fmax(1.0 - 2.0 * dot + x2c * y2, 1e-15);
      double Bc = 1.0 - x2c;
      double u2 = (A * A * x2c - 2.0 * A * Bc * dot + Bc * Bc * y2) / (Dn * Dn);
      double unr = sqrt(fmax(u2, 0.0));
      double un = fmax(unr, 1e-15);
      double coef = fmax(Bc, 1e-15) * atanh(fmin(un, 1.0 - 1e-7)) / un;
      double cs = wns[tid] * coef / Dn;
      sA[tid] = cs;
      sB[tid] = cs * A;
    }
    double S1 = reduceS_sum(sB, red, tid);   // syncs cover sA/sB writes
    double g = dsum16(sA, khB + tid);
    double xold = xc[tid];
    double Bc = 1.0 - x2c;
    double vg = Bc * g - S1 * xold;           // v_grad[d]
    double nv2 = blockSum(vg * vg, red, tid);
    double nv = 0.1 * sqrt(nv2);
    double cf = fmin(4.0 / (nv + 1e-8), 1.0);
    double nw = fmax(nv * cf, 1e-15);
    double tsc = tanh(nw / fmax(Bc, 1e-15));
    double zco = tsc * 0.1 * cf / nw;
    double z = zco * vg;
    double xz = blockSum(xold * z, red, tid);
    double z2 = tsc * tsc;
    double den = fmax(1.0 + 2.0 * xz + x2c * z2, 1e-15);
    double xnew = ((1.0 + 2.0 * xz + z2) * xold + (1.0 - x2c) * z) / den;
    xc[tid] = xnew;
    x2c = blockSum(xnew * xnew, red, tid);    // syncs cover xc write
  }

  // ---- k_centroid = projx(mu + noise) ----
  {
    double cn = xc[tid] + noiseval;
    double n2 = blockSum(cn * cn, red, tid);
    double nn = sqrt(n2);
    if (nn > 1.0 - 1e-5) cn *= (1.0 - 1e-5) / fmax(nn, 1e-15);
    xc[tid] = cn;
    x2c = blockSum(cn * cn, red, tid);        // syncs cover xc write
  }

  // ---- c2k distances, entropy, variance; alf/bet for weighted_k ----
  if (tid < SS) {
    double dot = sdot2(xc, khT2B);
    double y2 = y2s[tid];
    double A = 1.0 - 2.0 * dot + y2;
    double Dn = fmax(1.0 - 2.0 * dot + x2c * y2, 1e-15);
    double Bc = 1.0 - x2c;
    double u2 = (A * A * x2c - 2.0 * A * Bc * dot + Bc * Bc * y2) / (Dn * Dn);
    double unr = sqrt(fmax(u2, 0.0));
    double c2k = 2.0 * atanh(fmin(unr, 1.0 - 1e-7));
    sA[tid] = wns[tid] * c2k * c2k;
    sB[tid] = -wns[tid] * log(wns[tid] + 1e-8);
    double un = fmax(unr, 1e-15);
    double gl = fmax(Bc, 1e-15) * atanh(fmin(un, 1.0 - 1e-7)) / (un * Dn);
    double sq = sqrt(wun[tid] + 1e-8);
    alf[tid] = -sq * gl * A;
    bet[tid] = sq * gl * Bc;
  }
  double variance = reduceS_sum(sA, red, tid);
  double entropy = reduceS_sum(sB, red, tid);
  double tau = (double)tau_p[0];
  double tension = variance - tau * exp(entropy);

  // ---- power iteration on weighted_k (rank-structured) ----
  {
    double n2 = blockSum(vrndval * vrndval, red, tid);
    vr[tid] = vrndval / fmax(sqrt(n2), 1e-8);
  }
  for (int it = 0; it < 3; ++it) {
    double dxv = blockSum(xc[tid] * vr[tid], red, tid);  // syncs cover vr write
    if (tid < SS) {
      double dot = sdot2(vr, khT2B);
      double pj = alf[tid] * dxv + bet[tid] * dot;
      sA[tid] = alf[tid] * pj;
      sB[tid] = bet[tid] * pj;
    }
    double T1 = reduceS_sum(sA, red, tid);
    double g = dsum16(sB, khB + tid);
    double vnew = T1 * xc[tid] + g;
    double n2 = blockSum(vnew * vnew, red, tid);
    vr[tid] = vnew / fmax(sqrt(n2), 1e-8);
  }

  // ---- w_proj ----
  double wproj;
  {
    double wg = vr[tid] / fmax(1.0 - x2c, 1e-15);
    double nq = fmax(sqrt(x2q), 1e-15);
    double aq = atanh(fmin(nq, 1.0 - 1e-7)) / nq;
    double nc = fmax(sqrt(x2c), 1e-15);
    double ac = atanh(fmin(nc, 1.0 - 1e-7)) / nc;
    double f = aq * xq[tid] - ac * xc[tid];
    double n2 = blockSum(f * f, red, tid);
    double fb = f / fmax(sqrt(n2), 1e-8);
    wproj = (variance > 1e-5) ? wg : fb;
  }

  // ---- h_comp, x, pitchfork RK4 ----
  double hn2 = blockSum(hreg * hreg, red, tid);
  double hn = sqrt(hn2);
  double hsc = asinh(hn) / (hn + 1e-8);
  double hc = hsc * hreg;
  double x = blockSum(hc * wproj, red, tid);
  double xi = (x == 0.0) ? odeval : x;
  const double dt = 0.5;
#pragma unroll
  for (int r = 0; r < 4; ++r) {
    double k1 = dt * (tension * xi - xi * xi * xi);
    double a2 = xi + 0.5 * k1;
    double k2 = dt * (tension * a2 - a2 * a2 * a2);
    double a3 = xi + 0.5 * k2;
    double k3 = dt * (tension * a3 - a3 * a3 * a3);
    double a4 = xi + k3;
    double k4 = dt * (tension * a4 - a4 * a4 * a4);
    xi += (k1 + 2.0 * k2 + 2.0 * k3 + k4) / 6.0;
  }
  double ts = (double)ts_p[0];
  double hp = (hc + (xi - x) * wproj) * ts;
  double hp2 = blockSum(hp * hp, red, tid);
  double nhp = sqrt(hp2);
  double cf = fmin(4.0 / (nhp + 1e-8), 1.0);
  double ncl = fmax(nhp * cf, 1e-15);
  double th = tanh(ncl);
  double nb = fmax(th, 1e-15);
  double ab = atanh(fmin(nb, 1.0 - 1e-7)) / nb;
  double hob = ab * th * cf / ncl * hp;
  double gate = fmax(tanh(tension / fmax(tau, 1e-3)), 0.0);

  // ---- fused output GEMM: out[row] = h_fused . Wo^T + bo ----
  hfl[tid] = (float)((1.0 - gate) * hreg + gate * hob);
  __syncthreads();
  double o = rowdot(hfl, Wo + (size_t)tid * DD) + (double)bo[tid];
  out[rowOff + tid] = (float)o;
}

// ---------------- launch ----------------
extern "C" void kernel_launch(void* const* d_in, const int* in_sizes, int n_in,
                              void* d_out, int out_size, void* d_ws, size_t ws_size,
                              hipStream_t stream) {
  const float* q_in = (const float*)d_in[0];
  const float* k_in = (const float*)d_in[1];
  const float* v_in = (const float*)d_in[2];
  const float* Wq = (const float*)d_in[3];
  const float* bq = (const float*)d_in[4];
  const float* Wk = (const float*)d_in[5];
  const float* bk = (const float*)d_in[6];
  const float* Wv = (const float*)d_in[7];
  const float* bv = (const float*)d_in[8];
  const float* Wo = (const float*)d_in[9];
  const float* bo = (const float*)d_in[10];
  const float* tau = (const float*)d_in[11];
  const float* ts = (const float*)d_in[12];
  float* out = (float*)d_out;
  (void)in_sizes; (void)n_in; (void)out_size; (void)ws_size;

  char* base = (char*)d_ws;
  size_t off = 0;
  auto alloc = [&](size_t bytes) -> void* {
    void* p = base + off;
    off += (bytes + 255) & ~(size_t)255;
    return p;
  };
  float* kb = (float*)alloc((size_t)NE * 4);
  float* vb = (float*)alloc((size_t)NE * 4);
  float* qh = (float*)alloc((size_t)NE * 4);
  float* kh = (float*)alloc((size_t)NE * 4);
  float2* khT2 = (float2*)alloc((size_t)NE * 4);  // B * (DD/2) * SS float2
  double* y2g = (double*)alloc((size_t)NROW * 8);

  hipLaunchKernelGGL(proj_kernel, dim3(NROW, 3), dim3(DD), 0, stream,
                     q_in, k_in, v_in, Wq, Wk, Wv, bq, bk, bv,
                     qh, kb, vb, kh, khT2, y2g);
  hipLaunchKernelGGL(resonance_main, dim3(NROW), dim3(DD), 0, stream,
                     qh, kh, khT2, kb, vb, y2g, Wo, bo, tau, ts, out);
}

// Round 6
// 352.362 us; speedup vs baseline: 2.3643x; 2.3643x over previous
//
#include <hip/hip_runtime.h>
#include <hip/hip_bf16.h>
#include <stdint.h>

#define BB 2
#define SS 192
#define DD 256
#define NROW (BB * SS)   // 384
#define NE (NROW * DD)   // 98304

// ---------------- threefry2x32-20 (Random123 / JAX, partitionable) ----------------
__device__ __forceinline__ uint32_t rotl32(uint32_t v, int d) {
  return (v << d) | (v >> (32 - d));
}

__device__ inline void threefry2x32(uint32_t k0, uint32_t k1, uint32_t x0, uint32_t x1,
                                    uint32_t* o0, uint32_t* o1) {
  uint32_t ks2 = k0 ^ k1 ^ 0x1BD11BDAu;
  x0 += k0; x1 += k1;
  const int ra[4] = {13, 15, 26, 6};
  const int rb[4] = {17, 29, 16, 24};
#pragma unroll
  for (int i = 0; i < 4; i++) { x0 += x1; x1 = rotl32(x1, ra[i]); x1 ^= x0; }
  x0 += k1; x1 += ks2 + 1u;
#pragma unroll
  for (int i = 0; i < 4; i++) { x0 += x1; x1 = rotl32(x1, rb[i]); x1 ^= x0; }
  x0 += ks2; x1 += k0 + 2u;
#pragma unroll
  for (int i = 0; i < 4; i++) { x0 += x1; x1 = rotl32(x1, ra[i]); x1 ^= x0; }
  x0 += k0; x1 += k1 + 3u;
#pragma unroll
  for (int i = 0; i < 4; i++) { x0 += x1; x1 = rotl32(x1, rb[i]); x1 ^= x0; }
  x0 += k1; x1 += ks2 + 4u;
#pragma unroll
  for (int i = 0; i < 4; i++) { x0 += x1; x1 = rotl32(x1, ra[i]); x1 ^= x0; }
  x0 += ks2; x1 += k0 + 5u;
  *o0 = x0; *o1 = x1;
}

__device__ inline float erfinv_xla_f32(float x) {
  float w = -log1pf(-x * x);
  float p;
  if (w < 5.0f) {
    w = w - 2.5f;
    p = 2.81022636e-08f;
    p = 3.43273939e-07f + p * w;
    p = -3.5233877e-06f + p * w;
    p = -4.39150654e-06f + p * w;
    p = 0.00021858087f + p * w;
    p = -0.00125372503f + p * w;
    p = -0.00417768164f + p * w;
    p = 0.246640727f + p * w;
    p = 1.50140941f + p * w;
  } else {
    w = sqrtf(w) - 3.0f;
    p = -0.000200214257f;
    p = 0.000100950558f + p * w;
    p = 0.00134934322f + p * w;
    p = -0.00367342844f + p * w;
    p = 0.00573950773f + p * w;
    p = -0.0076224613f + p * w;
    p = 0.00943887047f + p * w;
    p = 1.00167406f + p * w;
    p = 2.83297682f + p * w;
  }
  return p * x;
}

__device__ inline float jax_normal_from_bits(uint32_t bits) {
  float f = __uint_as_float((bits >> 9) | 0x3f800000u) - 1.0f;
  const float lo = -0.99999994f;  // nextafter(-1, 0)
  float u = f * (1.0f - lo) + lo;
  u = fmaxf(lo, u);
  return 1.4142135623730951f * erfinv_xla_f32(u);
}

__device__ inline float jax_normal_at(uint32_t ka, uint32_t kb, uint32_t i) {
  uint32_t o0, o1;
  threefry2x32(ka, kb, 0u, i, &o0, &o1);
  return jax_normal_from_bits(o0 ^ o1);
}

// ---------------- reductions (256 threads = 4 waves of 64) ----------------
__device__ inline double blockSum(double v, double* red, int tid) {
#pragma unroll
  for (int o = 32; o > 0; o >>= 1) v += __shfl_down(v, o, 64);
  __syncthreads();
  if ((tid & 63) == 0) red[tid >> 6] = v;
  __syncthreads();
  return (red[0] + red[1]) + (red[2] + red[3]);
}

__device__ inline double reduceS_sum(const double* arr, double* red, int tid) {
  __syncthreads();
  if (tid < 64) {
    double v = arr[tid] + arr[tid + 64] + arr[tid + 128];
#pragma unroll
    for (int o = 32; o > 0; o >>= 1) v += __shfl_down(v, o, 64);
    if (tid == 0) red[4] = v;
  }
  __syncthreads();
  return red[4];
}

__device__ inline double reduceS_min(const double* arr, double* red, int tid) {
  __syncthreads();
  if (tid < 64) {
    double v = fmin(arr[tid], fmin(arr[tid + 64], arr[tid + 128]));
#pragma unroll
    for (int o = 32; o > 0; o >>= 1) v = fmin(v, __shfl_down(v, o, 64));
    if (tid == 0) red[5] = v;
  }
  __syncthreads();
  return red[5];
}

// ============ single-set deep-staged dot kernels (no ping-pong; named regs) ============

// per-s dot over d: vec (LDS f64, read as double2) . khT2 column (float2, stride SS)
__device__ inline double sdot16(const double* __restrict__ vec, const float2* __restrict__ cb) {
  const double2* vp = (const double2*)vec;
  double A0=0,A1=0,A2=0,A3=0,A4=0,A5=0,A6=0,A7=0;
  double A8=0,A9=0,A10=0,A11=0,A12=0,A13=0,A14=0,A15=0;
  for (int d0 = 0; d0 < DD / 2; d0 += 16) {
    float2 f0  = cb[(size_t)(d0 + 0) * SS];
    float2 f1  = cb[(size_t)(d0 + 1) * SS];
    float2 f2  = cb[(size_t)(d0 + 2) * SS];
    float2 f3  = cb[(size_t)(d0 + 3) * SS];
    float2 f4  = cb[(size_t)(d0 + 4) * SS];
    float2 f5  = cb[(size_t)(d0 + 5) * SS];
    float2 f6  = cb[(size_t)(d0 + 6) * SS];
    float2 f7  = cb[(size_t)(d0 + 7) * SS];
    float2 f8  = cb[(size_t)(d0 + 8) * SS];
    float2 f9  = cb[(size_t)(d0 + 9) * SS];
    float2 f10 = cb[(size_t)(d0 + 10) * SS];
    float2 f11 = cb[(size_t)(d0 + 11) * SS];
    float2 f12 = cb[(size_t)(d0 + 12) * SS];
    float2 f13 = cb[(size_t)(d0 + 13) * SS];
    float2 f14 = cb[(size_t)(d0 + 14) * SS];
    float2 f15 = cb[(size_t)(d0 + 15) * SS];
    { double2 v_ = vp[d0 + 0];  A0  += v_.x * (double)f0.x;  A0  += v_.y * (double)f0.y;  }
    { double2 v_ = vp[d0 + 1];  A1  += v_.x * (double)f1.x;  A1  += v_.y * (double)f1.y;  }
    { double2 v_ = vp[d0 + 2];  A2  += v_.x * (double)f2.x;  A2  += v_.y * (double)f2.y;  }
    { double2 v_ = vp[d0 + 3];  A3  += v_.x * (double)f3.x;  A3  += v_.y * (double)f3.y;  }
    { double2 v_ = vp[d0 + 4];  A4  += v_.x * (double)f4.x;  A4  += v_.y * (double)f4.y;  }
    { double2 v_ = vp[d0 + 5];  A5  += v_.x * (double)f5.x;  A5  += v_.y * (double)f5.y;  }
    { double2 v_ = vp[d0 + 6];  A6  += v_.x * (double)f6.x;  A6  += v_.y * (double)f6.y;  }
    { double2 v_ = vp[d0 + 7];  A7  += v_.x * (double)f7.x;  A7  += v_.y * (double)f7.y;  }
    { double2 v_ = vp[d0 + 8];  A8  += v_.x * (double)f8.x;  A8  += v_.y * (double)f8.y;  }
    { double2 v_ = vp[d0 + 9];  A9  += v_.x * (double)f9.x;  A9  += v_.y * (double)f9.y;  }
    { double2 v_ = vp[d0 + 10]; A10 += v_.x * (double)f10.x; A10 += v_.y * (double)f10.y; }
    { double2 v_ = vp[d0 + 11]; A11 += v_.x * (double)f11.x; A11 += v_.y * (double)f11.y; }
    { double2 v_ = vp[d0 + 12]; A12 += v_.x * (double)f12.x; A12 += v_.y * (double)f12.y; }
    { double2 v_ = vp[d0 + 13]; A13 += v_.x * (double)f13.x; A13 += v_.y * (double)f13.y; }
    { double2 v_ = vp[d0 + 14]; A14 += v_.x * (double)f14.x; A14 += v_.y * (double)f14.y; }
    { double2 v_ = vp[d0 + 15]; A15 += v_.x * (double)f15.x; A15 += v_.y * (double)f15.y; }
  }
  double s0 = ((A0 + A1) + (A2 + A3)) + ((A4 + A5) + (A6 + A7));
  double s1 = ((A8 + A9) + (A10 + A11)) + ((A12 + A13) + (A14 + A15));
  return s0 + s1;
}

// d-mapped weighted sum over s: sum_s w[s] * mb[s*DD]  (w in LDS f64)
__device__ inline double dsum16(const double* __restrict__ w, const float* __restrict__ mb) {
  double A0=0,A1=0,A2=0,A3=0,A4=0,A5=0,A6=0,A7=0;
  double A8=0,A9=0,A10=0,A11=0,A12=0,A13=0,A14=0,A15=0;
  for (int s0 = 0; s0 < SS; s0 += 16) {
    float f0  = mb[(size_t)(s0 + 0) * DD];
    float f1  = mb[(size_t)(s0 + 1) * DD];
    float f2  = mb[(size_t)(s0 + 2) * DD];
    float f3  = mb[(size_t)(s0 + 3) * DD];
    float f4  = mb[(size_t)(s0 + 4) * DD];
    float f5  = mb[(size_t)(s0 + 5) * DD];
    float f6  = mb[(size_t)(s0 + 6) * DD];
    float f7  = mb[(size_t)(s0 + 7) * DD];
    float f8  = mb[(size_t)(s0 + 8) * DD];
    float f9  = mb[(size_t)(s0 + 9) * DD];
    float f10 = mb[(size_t)(s0 + 10) * DD];
    float f11 = mb[(size_t)(s0 + 11) * DD];
    float f12 = mb[(size_t)(s0 + 12) * DD];
    float f13 = mb[(size_t)(s0 + 13) * DD];
    float f14 = mb[(size_t)(s0 + 14) * DD];
    float f15 = mb[(size_t)(s0 + 15) * DD];
    A0  += w[s0 + 0]  * (double)f0;
    A1  += w[s0 + 1]  * (double)f1;
    A2  += w[s0 + 2]  * (double)f2;
    A3  += w[s0 + 3]  * (double)f3;
    A4  += w[s0 + 4]  * (double)f4;
    A5  += w[s0 + 5]  * (double)f5;
    A6  += w[s0 + 6]  * (double)f6;
    A7  += w[s0 + 7]  * (double)f7;
    A8  += w[s0 + 8]  * (double)f8;
    A9  += w[s0 + 9]  * (double)f9;
    A10 += w[s0 + 10] * (double)f10;
    A11 += w[s0 + 11] * (double)f11;
    A12 += w[s0 + 12] * (double)f12;
    A13 += w[s0 + 13] * (double)f13;
    A14 += w[s0 + 14] * (double)f14;
    A15 += w[s0 + 15] * (double)f15;
  }
  double s0 = ((A0 + A1) + (A2 + A3)) + ((A4 + A5) + (A6 + A7));
  double s1 = ((A8 + A9) + (A10 + A11)) + ((A12 + A13) + (A14 + A15));
  return s0 + s1;
}

// fused h = w.v, mu = w.k : 8 v-loads + 8 k-loads outstanding per group
__device__ inline void hmu16(const double* __restrict__ w, const float* __restrict__ vbp,
                             const float* __restrict__ kbp, double& hout, double& muout) {
  double H0=0,H1=0,H2=0,H3=0,M0=0,M1=0,M2=0,M3=0;
  for (int s0 = 0; s0 < SS; s0 += 8) {
    float v0 = vbp[(size_t)(s0 + 0) * DD];
    float v1 = vbp[(size_t)(s0 + 1) * DD];
    float v2 = vbp[(size_t)(s0 + 2) * DD];
    float v3 = vbp[(size_t)(s0 + 3) * DD];
    float v4 = vbp[(size_t)(s0 + 4) * DD];
    float v5 = vbp[(size_t)(s0 + 5) * DD];
    float v6 = vbp[(size_t)(s0 + 6) * DD];
    float v7 = vbp[(size_t)(s0 + 7) * DD];
    float k0 = kbp[(size_t)(s0 + 0) * DD];
    float k1 = kbp[(size_t)(s0 + 1) * DD];
    float k2 = kbp[(size_t)(s0 + 2) * DD];
    float k3 = kbp[(size_t)(s0 + 3) * DD];
    float k4 = kbp[(size_t)(s0 + 4) * DD];
    float k5 = kbp[(size_t)(s0 + 5) * DD];
    float k6 = kbp[(size_t)(s0 + 6) * DD];
    float k7 = kbp[(size_t)(s0 + 7) * DD];
    double w0 = w[s0 + 0], w1 = w[s0 + 1], w2 = w[s0 + 2], w3 = w[s0 + 3];
    double w4 = w[s0 + 4], w5 = w[s0 + 5], w6 = w[s0 + 6], w7 = w[s0 + 7];
    H0 += w0 * (double)v0; M0 += w0 * (double)k0;
    H1 += w1 * (double)v1; M1 += w1 * (double)k1;
    H2 += w2 * (double)v2; M2 += w2 * (double)k2;
    H3 += w3 * (double)v3; M3 += w3 * (double)k3;
    H0 += w4 * (double)v4; M0 += w4 * (double)k4;
    H1 += w5 * (double)v5; M1 += w5 * (double)k5;
    H2 += w6 * (double)v6; M2 += w6 * (double)k6;
    H3 += w7 * (double)v7; M3 += w7 * (double)k7;
  }
  hout = (H0 + H1) + (H2 + H3);
  muout = (M0 + M1) + (M2 + M3);
}

// dot of LDS f32 vector (float4) with a contiguous W row (float4), 8-deep single-set
__device__ inline double rowdot(const float* __restrict__ xs, const float* __restrict__ wrow) {
  const float4* wp4 = (const float4*)wrow;
  const float4* xp = (const float4*)xs;
  double A0=0,A1=0,A2=0,A3=0,A4=0,A5=0,A6=0,A7=0;
  for (int i0 = 0; i0 < DD / 4; i0 += 8) {
    float4 c0 = wp4[i0 + 0];
    float4 c1 = wp4[i0 + 1];
    float4 c2 = wp4[i0 + 2];
    float4 c3 = wp4[i0 + 3];
    float4 c4 = wp4[i0 + 4];
    float4 c5 = wp4[i0 + 5];
    float4 c6 = wp4[i0 + 6];
    float4 c7 = wp4[i0 + 7];
    { float4 x_ = xp[i0 + 0]; A0 += (double)x_.x*(double)c0.x; A0 += (double)x_.y*(double)c0.y;
                              A0 += (double)x_.z*(double)c0.z; A0 += (double)x_.w*(double)c0.w; }
    { float4 x_ = xp[i0 + 1]; A1 += (double)x_.x*(double)c1.x; A1 += (double)x_.y*(double)c1.y;
                              A1 += (double)x_.z*(double)c1.z; A1 += (double)x_.w*(double)c1.w; }
    { float4 x_ = xp[i0 + 2]; A2 += (double)x_.x*(double)c2.x; A2 += (double)x_.y*(double)c2.y;
                              A2 += (double)x_.z*(double)c2.z; A2 += (double)x_.w*(double)c2.w; }
    { float4 x_ = xp[i0 + 3]; A3 += (double)x_.x*(double)c3.x; A3 += (double)x_.y*(double)c3.y;
                              A3 += (double)x_.z*(double)c3.z; A3 += (double)x_.w*(double)c3.w; }
    { float4 x_ = xp[i0 + 4]; A4 += (double)x_.x*(double)c4.x; A4 += (double)x_.y*(double)c4.y;
                              A4 += (double)x_.z*(double)c4.z; A4 += (double)x_.w*(double)c4.w; }
    { float4 x_ = xp[i0 + 5]; A5 += (double)x_.x*(double)c5.x; A5 += (double)x_.y*(double)c5.y;
                              A5 += (double)x_.z*(double)c5.z; A5 += (double)x_.w*(double)c5.w; }
    { float4 x_ = xp[i0 + 6]; A6 += (double)x_.x*(double)c6.x; A6 += (double)x_.y*(double)c6.y;
                              A6 += (double)x_.z*(double)c6.z; A6 += (double)x_.w*(double)c6.w; }
    { float4 x_ = xp[i0 + 7]; A7 += (double)x_.x*(double)c7.x; A7 += (double)x_.y*(double)c7.y;
                              A7 += (double)x_.z*(double)c7.z; A7 += (double)x_.w*(double)c7.w; }
  }
  return ((A0 + A1) + (A2 + A3)) + ((A4 + A5) + (A6 + A7));
}

// ---------------- fused QKV projection + expmap0 rows ----------------
__global__ __launch_bounds__(256) void proj_kernel(
    const float* __restrict__ q_in, const float* __restrict__ k_in, const float* __restrict__ v_in,
    const float* __restrict__ Wq, const float* __restrict__ Wk, const float* __restrict__ Wv,
    const float* __restrict__ bq, const float* __restrict__ bk, const float* __restrict__ bv,
    float* __restrict__ qh, float* __restrict__ kb, float* __restrict__ vb,
    float* __restrict__ kh, float2* __restrict__ khT2, double* __restrict__ y2g) {
  const int row = blockIdx.x, m = blockIdx.y, j = threadIdx.x;
  __shared__ __align__(16) float xs[DD];
  __shared__ double red[8];
  const float* x; const float* W; const float* bias;
  if (m == 0) { x = q_in; W = Wq; bias = bq; }
  else if (m == 1) { x = k_in; W = Wk; bias = bk; }
  else { x = v_in; W = Wv; bias = bv; }
  xs[j] = x[(size_t)row * DD + j];
  __syncthreads();
  double val = rowdot(xs, W + (size_t)j * DD) + (double)bias[j];

  if (m == 2) { vb[(size_t)row * DD + j] = (float)val; return; }

  double n2 = blockSum(val * val, red, j);
  double n = sqrt(n2);
  double cf = fmin(4.0 / (n + 1e-8), 1.0);
  double ncl = fmax(n * cf, 1e-15);
  double sc = tanh(ncl) * cf / ncl;
  if (m == 0) {
    qh[(size_t)row * DD + j] = (float)(val * sc);
  } else {
    kb[(size_t)row * DD + j] = (float)val;
    float khf = (float)(val * sc);
    kh[(size_t)row * DD + j] = khf;
    float hi = __shfl_down(khf, 1, 64);
    int bb = row / SS, s = row % SS;
    if (!(j & 1))
      khT2[((size_t)bb * (DD / 2) + (j >> 1)) * SS + s] = make_float2(khf, hi);
    double y2 = blockSum((double)khf * (double)khf, red, j);
    if (j == 0) y2g[row] = y2;
  }
}

// ---------------- main fused per-(b,q) kernel (output GEMM fused in) ----------------
__global__ __launch_bounds__(256) void resonance_main(
    const float* __restrict__ q_hyp, const float* __restrict__ k_hyp,
    const float2* __restrict__ khT2, const float* __restrict__ kmat,
    const float* __restrict__ vmat, const double* __restrict__ y2g,
    const float* __restrict__ Wo, const float* __restrict__ bo,
    const float* __restrict__ tau_p, const float* __restrict__ ts_p,
    float* __restrict__ out) {
  __shared__ __align__(16) double xq[DD], xc[DD], vr[DD];
  __shared__ __align__(16) double y2s[SS], wun[SS], wns[SS], alf[SS], bet[SS], sA[SS], sB[SS];
  __shared__ __align__(16) float hfl[DD];
  __shared__ double red[8];
  const int tid = threadIdx.x;
  const int blk = blockIdx.x;
  const int b = blk / SS;
  const size_t rowOff = (size_t)blk * DD;
  const float* khB = k_hyp + (size_t)b * SS * DD;
  const float2* khT2B = khT2 + (size_t)b * (DD / 2) * SS + tid;  // pre-offset by s=tid
  const float* kB = kmat + (size_t)b * SS * DD;
  const float* vB = vmat + (size_t)b * SS * DD;

  // inline JAX PRNG: nk = split(key(42), 3), partitionable scheme
  uint32_t nk0a, nk0b, nk1a, nk1b, nk2a, nk2b;
  threefry2x32(0u, 42u, 0u, 0u, &nk0a, &nk0b);
  threefry2x32(0u, 42u, 0u, 1u, &nk1a, &nk1b);
  threefry2x32(0u, 42u, 0u, 2u, &nk2a, &nk2b);
  const uint32_t ei = (uint32_t)(rowOff + tid);
  const double noiseval = 1e-5 * (double)jax_normal_at(nk0a, nk0b, ei);
  const double vrndval = (double)jax_normal_at(nk1a, nk1b, ei);
  const double odeval = 1e-4 * (double)jax_normal_at(nk2a, nk2b, (uint32_t)blk);

  double xqv = (double)q_hyp[rowOff + tid];
  xq[tid] = xqv;
  if (tid < SS) y2s[tid] = y2g[b * SS + tid];
  double x2q = blockSum(xqv * xqv, red, tid);  // syncs cover xq/y2s writes

  // ---- pairwise hyperbolic distance row ----
  if (tid < SS) {
    double dot = sdot16(xq, khT2B);
    double y2 = y2s[tid];
    double A = 1.0 - 2.0 * dot + y2;
    double Dn = fmax(1.0 - 2.0 * dot + x2q * y2, 1e-15);
    double Bc = 1.0 - x2q;
    double u2 = (A * A * x2q - 2.0 * A * Bc * dot + Bc * Bc * y2) / (Dn * Dn);
    double unr = sqrt(fmax(u2, 0.0));
    sA[tid] = 2.0 * atanh(fmin(unr, 1.0 - 1e-7));
  }
  double mind = reduceS_min(sA, red, tid);
  if (tid < SS) wun[tid] = exp(-(sA[tid] - mind));
  double wsum = reduceS_sum(wun, red, tid);
  if (tid < SS) wns[tid] = wun[tid] * (1.0 / (wsum + 1e-8));
  __syncthreads();

  // ---- fused: h = wns.v and mu_raw = wns.k ----
  double hreg, mu;
  hmu16(wns, vB + tid, kB + tid, hreg, mu);

  // ---- mu0 = expmap0(clip_tangent(mu)) ----
  double x2c;
  {
    double n2 = blockSum(mu * mu, red, tid);
    double n = sqrt(n2);
    double cf = fmin(4.0 / (n + 1e-8), 1.0);
    double ncl = fmax(n * cf, 1e-15);
    double th = tanh(ncl);
    xc[tid] = mu * (th * cf / ncl);
    x2c = th * th;
  }
  __syncthreads();

  // ---- Karcher flow: 3 Riemannian SGD steps ----
  for (int it = 0; it < 3; ++it) {
    if (tid < SS) {
      double dot = sdot16(xc, khT2B);
      double y2 = y2s[tid];
      double A = 1.0 - 2.0 * dot + y2;
      double Dn = fmax(1.0 - 2.0 * dot + x2c * y2, 1e-15);
      double Bc = 1.0 - x2c;
      double u2 = (A * A * x2c - 2.0 * A * Bc * dot + Bc * Bc * y2) / (Dn * Dn);
      double unr = sqrt(fmax(u2, 0.0));
      double un = fmax(unr, 1e-15);
      double coef = fmax(Bc, 1e-15) * atanh(fmin(un, 1.0 - 1e-7)) / un;
      double cs = wns[tid] * coef / Dn;
      sA[tid] = cs;
      sB[tid] = cs * A;
    }
    double S1 = reduceS_sum(sB, red, tid);   // syncs cover sA/sB writes
    double g = dsum16(sA, khB + tid);
    double xold = xc[tid];
    double Bc = 1.0 - x2c;
    double vg = Bc * g - S1 * xold;           // v_grad[d]
    double nv2 = blockSum(vg * vg, red, tid);
    double nv = 0.1 * sqrt(nv2);
    double cf = fmin(4.0 / (nv + 1e-8), 1.0);
    double nw = fmax(nv * cf, 1e-15);
    double tsc = tanh(nw / fmax(Bc, 1e-15));
    double zco = tsc * 0.1 * cf / nw;
    double z = zco * vg;
    double xz = blockSum(xold * z, red, tid);
    double z2 = tsc * tsc;
    double den = fmax(1.0 + 2.0 * xz + x2c * z2, 1e-15);
    double xnew = ((1.0 + 2.0 * xz + z2) * xold + (1.0 - x2c) * z) / den;
    xc[tid] = xnew;
    x2c = blockSum(xnew * xnew, red, tid);    // syncs cover xc write
  }

  // ---- k_centroid = projx(mu + noise) ----
  {
    double cn = xc[tid] + noiseval;
    double n2 = blockSum(cn * cn, red, tid);
    double nn = sqrt(n2);
    if (nn > 1.0 - 1e-5) cn *= (1.0 - 1e-5) / fmax(nn, 1e-15);
    xc[tid] = cn;
    x2c = blockSum(cn * cn, red, tid);        // syncs cover xc write
  }

  // ---- c2k distances, entropy, variance; alf/bet for weighted_k ----
  if (tid < SS) {
    double dot = sdot16(xc, khT2B);
    double y2 = y2s[tid];
    double A = 1.0 - 2.0 * dot + y2;
    double Dn = fmax(1.0 - 2.0 * dot + x2c * y2, 1e-15);
    double Bc = 1.0 - x2c;
    double u2 = (A * A * x2c - 2.0 * A * Bc * dot + Bc * Bc * y2) / (Dn * Dn);
    double unr = sqrt(fmax(u2, 0.0));
    double c2k = 2.0 * atanh(fmin(unr, 1.0 - 1e-7));
    sA[tid] = wns[tid] * c2k * c2k;
    sB[tid] = -wns[tid] * log(wns[tid] + 1e-8);
    double un = fmax(unr, 1e-15);
    double gl = fmax(Bc, 1e-15) * atanh(fmin(un, 1.0 - 1e-7)) / (un * Dn);
    double sq = sqrt(wun[tid] + 1e-8);
    alf[tid] = -sq * gl * A;
    bet[tid] = sq * gl * Bc;
  }
  double variance = reduceS_sum(sA, red, tid);
  double entropy = reduceS_sum(sB, red, tid);
  double tau = (double)tau_p[0];
  double tension = variance - tau * exp(entropy);

  // ---- power iteration on weighted_k (rank-structured) ----
  {
    double n2 = blockSum(vrndval * vrndval, red, tid);
    vr[tid] = vrndval / fmax(sqrt(n2), 1e-8);
  }
  for (int it = 0; it < 3; ++it) {
    double dxv = blockSum(xc[tid] * vr[tid], red, tid);  // syncs cover vr write
    if (tid < SS) {
      double dot = sdot16(vr, khT2B);
      double pj = alf[tid] * dxv + bet[tid] * dot;
      sA[tid] = alf[tid] * pj;
      sB[tid] = bet[tid] * pj;
    }
    double T1 = reduceS_sum(sA, red, tid);
    double g = dsum16(sB, khB + tid);
    double vnew = T1 * xc[tid] + g;
    double n2 = blockSum(vnew * vnew, red, tid);
    vr[tid] = vnew / fmax(sqrt(n2), 1e-8);
  }

  // ---- w_proj ----
  double wproj;
  {
    double wg = vr[tid] / fmax(1.0 - x2c, 1e-15);
    double nq = fmax(sqrt(x2q), 1e-15);
    double aq = atanh(fmin(nq, 1.0 - 1e-7)) / nq;
    double nc = fmax(sqrt(x2c), 1e-15);
    double ac = atanh(fmin(nc, 1.0 - 1e-7)) / nc;
    double f = aq * xq[tid] - ac * xc[tid];
    double n2 = blockSum(f * f, red, tid);
    double fb = f / fmax(sqrt(n2), 1e-8);
    wproj = (variance > 1e-5) ? wg : fb;
  }

  // ---- h_comp, x, pitchfork RK4 ----
  double hn2 = blockSum(hreg * hreg, red, tid);
  double hn = sqrt(hn2);
  double hsc = asinh(hn) / (hn + 1e-8);
  double hc = hsc * hreg;
  double x = blockSum(hc * wproj, red, tid);
  double xi = (x == 0.0) ? odeval : x;
  const double dt = 0.5;
#pragma unroll
  for (int r = 0; r < 4; ++r) {
    double k1 = dt * (tension * xi - xi * xi * xi);
    double a2 = xi + 0.5 * k1;
    double k2 = dt * (tension * a2 - a2 * a2 * a2);
    double a3 = xi + 0.5 * k2;
    double k3 = dt * (tension * a3 - a3 * a3 * a3);
    double a4 = xi + k3;
    double k4 = dt * (tension * a4 - a4 * a4 * a4);
    xi += (k1 + 2.0 * k2 + 2.0 * k3 + k4) / 6.0;
  }
  double ts = (double)ts_p[0];
  double hp = (hc + (xi - x) * wproj) * ts;
  double hp2 = blockSum(hp * hp, red, tid);
  double nhp = sqrt(hp2);
  double cf = fmin(4.0 / (nhp + 1e-8), 1.0);
  double ncl = fmax(nhp * cf, 1e-15);
  double th = tanh(ncl);
  double nb = fmax(th, 1e-15);
  double ab = atanh(fmin(nb, 1.0 - 1e-7)) / nb;
  double hob = ab * th * cf / ncl * hp;
  double gate = fmax(tanh(tension / fmax(tau, 1e-3)), 0.0);

  // ---- fused output GEMM: out[row] = h_fused . Wo^T + bo ----
  hfl[tid] = (float)((1.0 - gate) * hreg + gate * hob);
  __syncthreads();
  double o = rowdot(hfl, Wo + (size_t)tid * DD) + (double)bo[tid];
  out[rowOff + tid] = (float)o;
}

// ---------------- launch ----------------
extern "C" void kernel_launch(void* const* d_in, const int* in_sizes, int n_in,
                              void* d_out, int out_size, void* d_ws, size_t ws_size,
                              hipStream_t stream) {
  const float* q_in = (const float*)d_in[0];
  const float* k_in = (const float*)d_in[1];
  const float* v_in = (const float*)d_in[2];
  const float* Wq = (const float*)d_in[3];
  const float* bq = (const float*)d_in[4];
  const float* Wk = (const float*)d_in[5];
  const float* bk = (const float*)d_in[6];
  const float* Wv = (const float*)d_in[7];
  const float* bv = (const float*)d_in[8];
  const float* Wo = (const float*)d_in[9];
  const float* bo = (const float*)d_in[10];
  const float* tau = (const float*)d_in[11];
  const float* ts = (const float*)d_in[12];
  float* out = (float*)d_out;
  (void)in_sizes; (void)n_in; (void)out_size; (void)ws_size;

  char* base = (char*)d_ws;
  size_t off = 0;
  auto alloc = [&](size_t bytes) -> void* {
    void* p = base + off;
    off += (bytes + 255) & ~(size_t)255;
    return p;
  };
  float* kb = (float*)alloc((size_t)NE * 4);
  float* vb = (float*)alloc((size_t)NE * 4);
  float* qh = (float*)alloc((size_t)NE * 4);
  float* kh = (float*)alloc((size_t)NE * 4);
  float2* khT2 = (float2*)alloc((size_t)NE * 4);  // B * (DD/2) * SS float2
  double* y2g = (double*)alloc((size_t)NROW * 8);

  hipLaunchKernelGGL(proj_kernel, dim3(NROW, 3), dim3(DD), 0, stream,
                     q_in, k_in, v_in, Wq, Wk, Wv, bq, bk, bv,
                     qh, kb, vb, kh, khT2, y2g);
  hipLaunchKernelGGL(resonance_main, dim3(NROW), dim3(DD), 0, stream,
                     qh, kh, khT2, kb, vb, y2g, Wo, bo, tau, ts, out);
}

// Round 7
// 195.933 us; speedup vs baseline: 4.2520x; 1.7984x over previous
//
#include <hip/hip_runtime.h>
#include <hip/hip_bf16.h>
#include <stdint.h>

#define BB 2
#define SS 192
#define DD 256
#define NROW (BB * SS)   // 384
#define NE (NROW * DD)   // 98304

// ---------------- threefry2x32-20 (Random123 / JAX, partitionable) ----------------
__device__ __forceinline__ uint32_t rotl32(uint32_t v, int d) {
  return (v << d) | (v >> (32 - d));
}

__device__ inline void threefry2x32(uint32_t k0, uint32_t k1, uint32_t x0, uint32_t x1,
                                    uint32_t* o0, uint32_t* o1) {
  uint32_t ks2 = k0 ^ k1 ^ 0x1BD11BDAu;
  x0 += k0; x1 += k1;
  const int ra[4] = {13, 15, 26, 6};
  const int rb[4] = {17, 29, 16, 24};
#pragma unroll
  for (int i = 0; i < 4; i++) { x0 += x1; x1 = rotl32(x1, ra[i]); x1 ^= x0; }
  x0 += k1; x1 += ks2 + 1u;
#pragma unroll
  for (int i = 0; i < 4; i++) { x0 += x1; x1 = rotl32(x1, rb[i]); x1 ^= x0; }
  x0 += ks2; x1 += k0 + 2u;
#pragma unroll
  for (int i = 0; i < 4; i++) { x0 += x1; x1 = rotl32(x1, ra[i]); x1 ^= x0; }
  x0 += k0; x1 += k1 + 3u;
#pragma unroll
  for (int i = 0; i < 4; i++) { x0 += x1; x1 = rotl32(x1, rb[i]); x1 ^= x0; }
  x0 += k1; x1 += ks2 + 4u;
#pragma unroll
  for (int i = 0; i < 4; i++) { x0 += x1; x1 = rotl32(x1, ra[i]); x1 ^= x0; }
  x0 += ks2; x1 += k0 + 5u;
  *o0 = x0; *o1 = x1;
}

__device__ inline float erfinv_xla_f32(float x) {
  float w = -log1pf(-x * x);
  float p;
  if (w < 5.0f) {
    w = w - 2.5f;
    p = 2.81022636e-08f;
    p = 3.43273939e-07f + p * w;
    p = -3.5233877e-06f + p * w;
    p = -4.39150654e-06f + p * w;
    p = 0.00021858087f + p * w;
    p = -0.00125372503f + p * w;
    p = -0.00417768164f + p * w;
    p = 0.246640727f + p * w;
    p = 1.50140941f + p * w;
  } else {
    w = sqrtf(w) - 3.0f;
    p = -0.000200214257f;
    p = 0.000100950558f + p * w;
    p = 0.00134934322f + p * w;
    p = -0.00367342844f + p * w;
    p = 0.00573950773f + p * w;
    p = -0.0076224613f + p * w;
    p = 0.00943887047f + p * w;
    p = 1.00167406f + p * w;
    p = 2.83297682f + p * w;
  }
  return p * x;
}

__device__ inline float jax_normal_from_bits(uint32_t bits) {
  float f = __uint_as_float((bits >> 9) | 0x3f800000u) - 1.0f;
  const float lo = -0.99999994f;  // nextafter(-1, 0)
  float u = f * (1.0f - lo) + lo;
  u = fmaxf(lo, u);
  return 1.4142135623730951f * erfinv_xla_f32(u);
}

__device__ inline float jax_normal_at(uint32_t ka, uint32_t kb, uint32_t i) {
  uint32_t o0, o1;
  threefry2x32(ka, kb, 0u, i, &o0, &o1);
  return jax_normal_from_bits(o0 ^ o1);
}

// ---------------- reductions (256 threads = 4 waves of 64) ----------------
__device__ inline double blockSum(double v, double* red, int tid) {
#pragma unroll
  for (int o = 32; o > 0; o >>= 1) v += __shfl_down(v, o, 64);
  __syncthreads();
  if ((tid & 63) == 0) red[tid >> 6] = v;
  __syncthreads();
  return (red[0] + red[1]) + (red[2] + red[3]);
}

__device__ inline double reduceS_sum(const double* arr, double* red, int tid) {
  __syncthreads();
  if (tid < 64) {
    double v = arr[tid] + arr[tid + 64] + arr[tid + 128];
#pragma unroll
    for (int o = 32; o > 0; o >>= 1) v += __shfl_down(v, o, 64);
    if (tid == 0) red[4] = v;
  }
  __syncthreads();
  return red[4];
}

__device__ inline double reduceS_min(const double* arr, double* red, int tid) {
  __syncthreads();
  if (tid < 64) {
    double v = fmin(arr[tid], fmin(arr[tid + 64], arr[tid + 128]));
#pragma unroll
    for (int o = 32; o > 0; o >>= 1) v = fmin(v, __shfl_down(v, o, 64));
    if (tid == 0) red[5] = v;
  }
  __syncthreads();
  return red[5];
}

// ---- sdot4: per-s dot over d. khT4 column (float4, stride SS), 8 staged float4,
//      8 f64 accumulators (round-4 register shape, 4x fewer latency groups). ----
__device__ inline double sdot4(const double* __restrict__ vec, const float4* __restrict__ cb) {
  const double2* vp = (const double2*)vec;
  double A0=0,A1=0,A2=0,A3=0,A4=0,A5=0,A6=0,A7=0;
  for (int g = 0; g < DD / 4; g += 8) {
    float4 f0 = cb[(size_t)(g + 0) * SS];
    float4 f1 = cb[(size_t)(g + 1) * SS];
    float4 f2 = cb[(size_t)(g + 2) * SS];
    float4 f3 = cb[(size_t)(g + 3) * SS];
    float4 f4 = cb[(size_t)(g + 4) * SS];
    float4 f5 = cb[(size_t)(g + 5) * SS];
    float4 f6 = cb[(size_t)(g + 6) * SS];
    float4 f7 = cb[(size_t)(g + 7) * SS];
    { double2 a = vp[2*(g+0)], b = vp[2*(g+0)+1];
      A0 += a.x*(double)f0.x; A0 += a.y*(double)f0.y; A0 += b.x*(double)f0.z; A0 += b.y*(double)f0.w; }
    { double2 a = vp[2*(g+1)], b = vp[2*(g+1)+1];
      A1 += a.x*(double)f1.x; A1 += a.y*(double)f1.y; A1 += b.x*(double)f1.z; A1 += b.y*(double)f1.w; }
    { double2 a = vp[2*(g+2)], b = vp[2*(g+2)+1];
      A2 += a.x*(double)f2.x; A2 += a.y*(double)f2.y; A2 += b.x*(double)f2.z; A2 += b.y*(double)f2.w; }
    { double2 a = vp[2*(g+3)], b = vp[2*(g+3)+1];
      A3 += a.x*(double)f3.x; A3 += a.y*(double)f3.y; A3 += b.x*(double)f3.z; A3 += b.y*(double)f3.w; }
    { double2 a = vp[2*(g+4)], b = vp[2*(g+4)+1];
      A4 += a.x*(double)f4.x; A4 += a.y*(double)f4.y; A4 += b.x*(double)f4.z; A4 += b.y*(double)f4.w; }
    { double2 a = vp[2*(g+5)], b = vp[2*(g+5)+1];
      A5 += a.x*(double)f5.x; A5 += a.y*(double)f5.y; A5 += b.x*(double)f5.z; A5 += b.y*(double)f5.w; }
    { double2 a = vp[2*(g+6)], b = vp[2*(g+6)+1];
      A6 += a.x*(double)f6.x; A6 += a.y*(double)f6.y; A6 += b.x*(double)f6.z; A6 += b.y*(double)f6.w; }
    { double2 a = vp[2*(g+7)], b = vp[2*(g+7)+1];
      A7 += a.x*(double)f7.x; A7 += a.y*(double)f7.y; A7 += b.x*(double)f7.z; A7 += b.y*(double)f7.w; }
  }
  return ((A0 + A1) + (A2 + A3)) + ((A4 + A5) + (A6 + A7));
}

// d-mapped weighted sum over s (round-4 exact shape): sum_s w[s] * mb[s*DD]
#define DSUM(wArr, mat, outv) do {                                           \
    const float* mb_ = (mat);                                                \
    double s0_=0.0,s1_=0.0,s2_=0.0,s3_=0.0,s4_=0.0,s5_=0.0,s6_=0.0,s7_=0.0;  \
    for (int t0_ = 0; t0_ < SS; t0_ += 8) {                                  \
      float f0_ = mb_[(size_t)(t0_ + 0) * DD];                               \
      float f1_ = mb_[(size_t)(t0_ + 1) * DD];                               \
      float f2_ = mb_[(size_t)(t0_ + 2) * DD];                               \
      float f3_ = mb_[(size_t)(t0_ + 3) * DD];                               \
      float f4_ = mb_[(size_t)(t0_ + 4) * DD];                               \
      float f5_ = mb_[(size_t)(t0_ + 5) * DD];                               \
      float f6_ = mb_[(size_t)(t0_ + 6) * DD];                               \
      float f7_ = mb_[(size_t)(t0_ + 7) * DD];                               \
      s0_ += (wArr)[t0_ + 0] * (double)f0_;                                  \
      s1_ += (wArr)[t0_ + 1] * (double)f1_;                                  \
      s2_ += (wArr)[t0_ + 2] * (double)f2_;                                  \
      s3_ += (wArr)[t0_ + 3] * (double)f3_;                                  \
      s4_ += (wArr)[t0_ + 4] * (double)f4_;                                  \
      s5_ += (wArr)[t0_ + 5] * (double)f5_;                                  \
      s6_ += (wArr)[t0_ + 6] * (double)f6_;                                  \
      s7_ += (wArr)[t0_ + 7] * (double)f7_;                                  \
    }                                                                        \
    (outv) = ((s0_ + s1_) + (s2_ + s3_)) + ((s4_ + s5_) + (s6_ + s7_));      \
  } while (0)

// ---------------- W transpose (round-4) ----------------
__global__ void transpose4(const float* __restrict__ Wq, const float* __restrict__ Wk,
                           const float* __restrict__ Wv, const float* __restrict__ Wo,
                           float* __restrict__ WqT, float* __restrict__ WkT,
                           float* __restrict__ WvT, float* __restrict__ WoT) {
  int m = blockIdx.x >> 8;
  int i = blockIdx.x & 255;
  int j = threadIdx.x;
  const float* S_; float* D_;
  if (m == 0) { S_ = Wq; D_ = WqT; }
  else if (m == 1) { S_ = Wk; D_ = WkT; }
  else if (m == 2) { S_ = Wv; D_ = WvT; }
  else { S_ = Wo; D_ = WoT; }
  D_[i * DD + j] = S_[j * DD + i];
}

// dot of xs[LDS f32, len DD] with WT column j, 8 named f64 accumulators (round-4)
__device__ inline double colDot(const float* __restrict__ xs,
                                const float* __restrict__ WT, int j) {
  const float* cb = WT + j;
  double s0=0.0,s1=0.0,s2=0.0,s3=0.0,s4=0.0,s5=0.0,s6=0.0,s7=0.0;
  for (int i0 = 0; i0 < DD; i0 += 8) {
    float f0 = cb[(size_t)(i0 + 0) * DD];
    float f1 = cb[(size_t)(i0 + 1) * DD];
    float f2 = cb[(size_t)(i0 + 2) * DD];
    float f3 = cb[(size_t)(i0 + 3) * DD];
    float f4 = cb[(size_t)(i0 + 4) * DD];
    float f5 = cb[(size_t)(i0 + 5) * DD];
    float f6 = cb[(size_t)(i0 + 6) * DD];
    float f7 = cb[(size_t)(i0 + 7) * DD];
    s0 += (double)xs[i0 + 0] * (double)f0;
    s1 += (double)xs[i0 + 1] * (double)f1;
    s2 += (double)xs[i0 + 2] * (double)f2;
    s3 += (double)xs[i0 + 3] * (double)f3;
    s4 += (double)xs[i0 + 4] * (double)f4;
    s5 += (double)xs[i0 + 5] * (double)f5;
    s6 += (double)xs[i0 + 6] * (double)f6;
    s7 += (double)xs[i0 + 7] * (double)f7;
  }
  return ((s0 + s1) + (s2 + s3)) + ((s4 + s5) + (s6 + s7));
}

// ---------------- fused QKV projection + expmap0 rows (round-4 + khT4 pack) ----------------
__global__ __launch_bounds__(256) void proj_kernel(
    const float* __restrict__ q_in, const float* __restrict__ k_in, const float* __restrict__ v_in,
    const float* __restrict__ WqT, const float* __restrict__ WkT, const float* __restrict__ WvT,
    const float* __restrict__ bq, const float* __restrict__ bk, const float* __restrict__ bv,
    float* __restrict__ qh, float* __restrict__ kb, float* __restrict__ vb,
    float* __restrict__ kh, float4* __restrict__ khT4, double* __restrict__ y2g) {
  const int row = blockIdx.x, m = blockIdx.y, j = threadIdx.x;
  __shared__ float xs[DD];
  __shared__ double red[8];
  const float* x; const float* WT; const float* bias;
  if (m == 0) { x = q_in; WT = WqT; bias = bq; }
  else if (m == 1) { x = k_in; WT = WkT; bias = bk; }
  else { x = v_in; WT = WvT; bias = bv; }
  xs[j] = x[(size_t)row * DD + j];
  __syncthreads();
  double val = colDot(xs, WT, j) + (double)bias[j];

  if (m == 2) { vb[(size_t)row * DD + j] = (float)val; return; }

  double n2 = blockSum(val * val, red, j);
  double n = sqrt(n2);
  double cf = fmin(4.0 / (n + 1e-8), 1.0);
  double ncl = fmax(n * cf, 1e-15);
  double sc = tanh(ncl) * cf / ncl;
  if (m == 0) {
    qh[(size_t)row * DD + j] = (float)(val * sc);
  } else {
    kb[(size_t)row * DD + j] = (float)val;
    float khf = (float)(val * sc);
    kh[(size_t)row * DD + j] = khf;
    float h1 = __shfl_down(khf, 1, 64);
    float h2 = __shfl_down(khf, 2, 64);
    float h3 = __shfl_down(khf, 3, 64);
    int bb = row / SS, s = row % SS;
    if (!(j & 3))
      khT4[((size_t)bb * (DD / 4) + (j >> 2)) * SS + s] = make_float4(khf, h1, h2, h3);
    double y2 = blockSum((double)khf * (double)khf, red, j);
    if (j == 0) y2g[row] = y2;
  }
}

// ---------------- main fused per-(b,q) kernel (output GEMM fused, WoT columns) ----------------
__global__ __launch_bounds__(256) void resonance_main(
    const float* __restrict__ q_hyp, const float* __restrict__ k_hyp,
    const float4* __restrict__ khT4, const float* __restrict__ kmat,
    const float* __restrict__ vmat, const double* __restrict__ y2g,
    const float* __restrict__ WoT, const float* __restrict__ bo,
    const float* __restrict__ tau_p, const float* __restrict__ ts_p,
    float* __restrict__ out) {
  __shared__ __align__(16) double xq[DD], xc[DD], vr[DD];
  __shared__ double y2s[SS], wun[SS], wns[SS], alf[SS], bet[SS], sA[SS], sB[SS];
  __shared__ float hfl[DD];
  __shared__ double red[8];
  const int tid = threadIdx.x;
  const int blk = blockIdx.x;
  const int b = blk / SS;
  const size_t rowOff = (size_t)blk * DD;
  const float* khB = k_hyp + (size_t)b * SS * DD;
  const float4* khT4B = khT4 + (size_t)b * (DD / 4) * SS + tid;  // pre-offset by s=tid
  const float* kB = kmat + (size_t)b * SS * DD;
  const float* vB = vmat + (size_t)b * SS * DD;

  // inline JAX PRNG: nk = split(key(42), 3), partitionable scheme
  uint32_t nk0a, nk0b, nk1a, nk1b, nk2a, nk2b;
  threefry2x32(0u, 42u, 0u, 0u, &nk0a, &nk0b);
  threefry2x32(0u, 42u, 0u, 1u, &nk1a, &nk1b);
  threefry2x32(0u, 42u, 0u, 2u, &nk2a, &nk2b);
  const uint32_t ei = (uint32_t)(rowOff + tid);
  const double noiseval = 1e-5 * (double)jax_normal_at(nk0a, nk0b, ei);
  const double vrndval = (double)jax_normal_at(nk1a, nk1b, ei);
  const double odeval = 1e-4 * (double)jax_normal_at(nk2a, nk2b, (uint32_t)blk);

  double xqv = (double)q_hyp[rowOff + tid];
  xq[tid] = xqv;
  if (tid < SS) y2s[tid] = y2g[b * SS + tid];
  double x2q = blockSum(xqv * xqv, red, tid);  // syncs cover xq/y2s writes

  // ---- pairwise hyperbolic distance row ----
  if (tid < SS) {
    double dot = sdot4(xq, khT4B);
    double y2 = y2s[tid];
    double A = 1.0 - 2.0 * dot + y2;
    double Dn = fmax(1.0 - 2.0 * dot + x2q * y2, 1e-15);
    double Bc = 1.0 - x2q;
    double u2 = (A * A * x2q - 2.0 * A * Bc * dot + Bc * Bc * y2) / (Dn * Dn);
    double unr = sqrt(fmax(u2, 0.0));
    sA[tid] = 2.0 * atanh(fmin(unr, 1.0 - 1e-7));
  }
  double mind = reduceS_min(sA, red, tid);
  if (tid < SS) wun[tid] = exp(-(sA[tid] - mind));
  double wsum = reduceS_sum(wun, red, tid);
  if (tid < SS) wns[tid] = wun[tid] * (1.0 / (wsum + 1e-8));
  __syncthreads();

  // ---- fused: h = wns.v and mu_raw = wns.k (round-4 4+4 shape) ----
  double hreg, mu;
  {
    const float* vb_ = vB + tid;
    const float* kb_ = kB + tid;
    double h0=0.0,h1=0.0,h2=0.0,h3=0.0, m0=0.0,m1=0.0,m2=0.0,m3=0.0;
    for (int s0 = 0; s0 < SS; s0 += 4) {
      float v0 = vb_[(size_t)(s0 + 0) * DD];
      float v1 = vb_[(size_t)(s0 + 1) * DD];
      float v2 = vb_[(size_t)(s0 + 2) * DD];
      float v3 = vb_[(size_t)(s0 + 3) * DD];
      float k0 = kb_[(size_t)(s0 + 0) * DD];
      float k1 = kb_[(size_t)(s0 + 1) * DD];
      float k2 = kb_[(size_t)(s0 + 2) * DD];
      float k3 = kb_[(size_t)(s0 + 3) * DD];
      double w0 = wns[s0 + 0], w1 = wns[s0 + 1], w2 = wns[s0 + 2], w3 = wns[s0 + 3];
      h0 += w0 * (double)v0; h1 += w1 * (double)v1;
      h2 += w2 * (double)v2; h3 += w3 * (double)v3;
      m0 += w0 * (double)k0; m1 += w1 * (double)k1;
      m2 += w2 * (double)k2; m3 += w3 * (double)k3;
    }
    hreg = (h0 + h1) + (h2 + h3);
    mu = (m0 + m1) + (m2 + m3);
  }

  // ---- mu0 = expmap0(clip_tangent(mu)) ----
  double x2c;
  {
    double n2 = blockSum(mu * mu, red, tid);
    double n = sqrt(n2);
    double cf = fmin(4.0 / (n + 1e-8), 1.0);
    double ncl = fmax(n * cf, 1e-15);
    double th = tanh(ncl);
    xc[tid] = mu * (th * cf / ncl);
    x2c = th * th;
  }
  __syncthreads();

  // ---- Karcher flow: 3 Riemannian SGD steps ----
  for (int it = 0; it < 3; ++it) {
    if (tid < SS) {
      double dot = sdot4(xc, khT4B);
      double y2 = y2s[tid];
      double A = 1.0 - 2.0 * dot + y2;
      double Dn = fmax(1.0 - 2.0 * dot + x2c * y2, 1e-15);
      double Bc = 1.0 - x2c;
      double u2 = (A * A * x2c - 2.0 * A * Bc * dot + Bc * Bc * y2) / (Dn * Dn);
      double unr = sqrt(fmax(u2, 0.0));
      double un = fmax(unr, 1e-15);
      double coef = fmax(Bc, 1e-15) * atanh(fmin(un, 1.0 - 1e-7)) / un;
      double cs = wns[tid] * coef / Dn;
      sA[tid] = cs;
      sB[tid] = cs * A;
    }
    double S1 = reduceS_sum(sB, red, tid);   // syncs cover sA/sB writes
    double g;
    DSUM(sA, khB + tid, g);
    double xold = xc[tid];
    double Bc = 1.0 - x2c;
    double vg = Bc * g - S1 * xold;           // v_grad[d]
    double nv2 = blockSum(vg * vg, red, tid);
    double nv = 0.1 * sqrt(nv2);
    double cf = fmin(4.0 / (nv + 1e-8), 1.0);
    double nw = fmax(nv * cf, 1e-15);
    double tsc = tanh(nw / fmax(Bc, 1e-15));
    double zco = tsc * 0.1 * cf / nw;
    double z = zco * vg;
    double xz = blockSum(xold * z, red, tid);
    double z2 = tsc * tsc;
    double den = fmax(1.0 + 2.0 * xz + x2c * z2, 1e-15);
    double xnew = ((1.0 + 2.0 * xz + z2) * xold + (1.0 - x2c) * z) / den;
    xc[tid] = xnew;
    x2c = blockSum(xnew * xnew, red, tid);    // syncs cover xc write
  }

  // ---- k_centroid = projx(mu + noise) ----
  {
    double cn = xc[tid] + noiseval;
    double n2 = blockSum(cn * cn, red, tid);
    double nn = sqrt(n2);
    if (nn > 1.0 - 1e-5) cn *= (1.0 - 1e-5) / fmax(nn, 1e-15);
    xc[tid] = cn;
    x2c = blockSum(cn * cn, red, tid);        // syncs cover xc write
  }

  // ---- c2k distances, entropy, variance; alf/bet for weighted_k ----
  if (tid < SS) {
    double dot = sdot4(xc, khT4B);
    double y2 = y2s[tid];
    double A = 1.0 - 2.0 * dot + y2;
    double Dn = fmax(1.0 - 2.0 * dot + x2c * y2, 1e-15);
    double Bc = 1.0 - x2c;
    double u2 = (A * A * x2c - 2.0 * A * Bc * dot + Bc * Bc * y2) / (Dn * Dn);
    double unr = sqrt(fmax(u2, 0.0));
    double c2k = 2.0 * atanh(fmin(unr, 1.0 - 1e-7));
    sA[tid] = wns[tid] * c2k * c2k;
    sB[tid] = -wns[tid] * log(wns[tid] + 1e-8);
    double un = fmax(unr, 1e-15);
    double gl = fmax(Bc, 1e-15) * atanh(fmin(un, 1.0 - 1e-7)) / (un * Dn);
    double sq = sqrt(wun[tid] + 1e-8);
    alf[tid] = -sq * gl * A;
    bet[tid] = sq * gl * Bc;
  }
  double variance = reduceS_sum(sA, red, tid);
  double entropy = reduceS_sum(sB, red, tid);
  double tau = (double)tau_p[0];
  double tension = variance - tau * exp(entropy);

  // ---- power iteration on weighted_k (rank-structured) ----
  {
    double n2 = blockSum(vrndval * vrndval, red, tid);
    vr[tid] = vrndval / fmax(sqrt(n2), 1e-8);
  }
  for (int it = 0; it < 3; ++it) {
    double dxv = blockSum(xc[tid] * vr[tid], red, tid);  // syncs cover vr write
    if (tid < SS) {
      double dot = sdot4(vr, khT4B);
      double pj = alf[tid] * dxv + bet[tid] * dot;
      sA[tid] = alf[tid] * pj;
      sB[tid] = bet[tid] * pj;
    }
    double T1 = reduceS_sum(sA, red, tid);
    double g;
    DSUM(sB, khB + tid, g);
    double vnew = T1 * xc[tid] + g;
    double n2 = blockSum(vnew * vnew, red, tid);
    vr[tid] = vnew / fmax(sqrt(n2), 1e-8);
  }

  // ---- w_proj ----
  double wproj;
  {
    double wg = vr[tid] / fmax(1.0 - x2c, 1e-15);
    double nq = fmax(sqrt(x2q), 1e-15);
    double aq = atanh(fmin(nq, 1.0 - 1e-7)) / nq;
    double nc = fmax(sqrt(x2c), 1e-15);
    double ac = atanh(fmin(nc, 1.0 - 1e-7)) / nc;
    double f = aq * xq[tid] - ac * xc[tid];
    double n2 = blockSum(f * f, red, tid);
    double fb = f / fmax(sqrt(n2), 1e-8);
    wproj = (variance > 1e-5) ? wg : fb;
  }

  // ---- h_comp, x, pitchfork RK4 ----
  double hn2 = blockSum(hreg * hreg, red, tid);
  double hn = sqrt(hn2);
  double hsc = asinh(hn) / (hn + 1e-8);
  double hc = hsc * hreg;
  double x = blockSum(hc * wproj, red, tid);
  double xi = (x == 0.0) ? odeval : x;
  const double dt = 0.5;
#pragma unroll
  for (int r = 0; r < 4; ++r) {
    double k1 = dt * (tension * xi - xi * xi * xi);
    double a2 = xi + 0.5 * k1;
    double k2 = dt * (tension * a2 - a2 * a2 * a2);
    double a3 = xi + 0.5 * k2;
    double k3 = dt * (tension * a3 - a3 * a3 * a3);
    double a4 = xi + k3;
    double k4 = dt * (tension * a4 - a4 * a4 * a4);
    xi += (k1 + 2.0 * k2 + 2.0 * k3 + k4) / 6.0;
  }
  double ts = (double)ts_p[0];
  double hp = (hc + (xi - x) * wproj) * ts;
  double hp2 = blockSum(hp * hp, red, tid);
  double nhp = sqrt(hp2);
  double cf = fmin(4.0 / (nhp + 1e-8), 1.0);
  double ncl = fmax(nhp * cf, 1e-15);
  double th = tanh(ncl);
  double nb = fmax(th, 1e-15);
  double ab = atanh(fmin(nb, 1.0 - 1e-7)) / nb;
  double hob = ab * th * cf / ncl * hp;
  double gate = fmax(tanh(tension / fmax(tau, 1e-3)), 0.0);

  // ---- fused output GEMM (coalesced WoT columns, round-4 gemm_out pattern) ----
  hfl[tid] = (float)((1.0 - gate) * hreg + gate * hob);
  __syncthreads();
  double o = colDot(hfl, WoT, tid) + (double)bo[tid];
  out[rowOff + tid] = (float)o;
}

// ---------------- launch ----------------
extern "C" void kernel_launch(void* const* d_in, const int* in_sizes, int n_in,
                              void* d_out, int out_size, void* d_ws, size_t ws_size,
                              hipStream_t stream) {
  const float* q_in = (const float*)d_in[0];
  const float* k_in = (const float*)d_in[1];
  const float* v_in = (const float*)d_in[2];
  const float* Wq = (const float*)d_in[3];
  const float* bq = (const float*)d_in[4];
  const float* Wk = (const float*)d_in[5];
  const float* bk = (const float*)d_in[6];
  const float* Wv = (const float*)d_in[7];
  const float* bv = (const float*)d_in[8];
  const float* Wo = (const float*)d_in[9];
  const float* bo = (const float*)d_in[10];
  const float* tau = (const float*)d_in[11];
  const float* ts = (const float*)d_in[12];
  float* out = (float*)d_out;
  (void)in_sizes; (void)n_in; (void)out_size; (void)ws_size;

  char* base = (char*)d_ws;
  size_t off = 0;
  auto alloc = [&](size_t bytes) -> void* {
    void* p = base + off;
    off += (bytes + 255) & ~(size_t)255;
    return p;
  };
  float* WqT = (float*)alloc((size_t)DD * DD * 4);
  float* WkT = (float*)alloc((size_t)DD * DD * 4);
  float* WvT = (float*)alloc((size_t)DD * DD * 4);
  float* WoT = (float*)alloc((size_t)DD * DD * 4);
  float* kb = (float*)alloc((size_t)NE * 4);
  float* vb = (float*)alloc((size_t)NE * 4);
  float* qh = (float*)alloc((size_t)NE * 4);
  float* kh = (float*)alloc((size_t)NE * 4);
  float4* khT4 = (float4*)alloc((size_t)NE * 4);  // B * (DD/4) * SS float4
  double* y2g = (double*)alloc((size_t)NROW * 8);

  hipLaunchKernelGGL(transpose4, dim3(4 * DD), dim3(DD), 0, stream,
                     Wq, Wk, Wv, Wo, WqT, WkT, WvT, WoT);
  hipLaunchKernelGGL(proj_kernel, dim3(NROW, 3), dim3(DD), 0, stream,
                     q_in, k_in, v_in, WqT, WkT, WvT, bq, bk, bv,
                     qh, kb, vb, kh, khT4, y2g);
  hipLaunchKernelGGL(resonance_main, dim3(NROW), dim3(DD), 0, stream,
                     qh, kh, khT4, kb, vb, y2g, WoT, bo, tau, ts, out);
}

// Round 8
// 193.351 us; speedup vs baseline: 4.3088x; 1.0134x over previous
//
#include <hip/hip_runtime.h>
#include <hip/hip_bf16.h>
#include <stdint.h>

#define BB 2
#define SS 192
#define DD 256
#define NROW (BB * SS)   // 384
#define NE (NROW * DD)   // 98304

// ---------------- threefry2x32-20 (Random123 / JAX, partitionable) ----------------
__device__ __forceinline__ uint32_t rotl32(uint32_t v, int d) {
  return (v << d) | (v >> (32 - d));
}

__device__ inline void threefry2x32(uint32_t k0, uint32_t k1, uint32_t x0, uint32_t x1,
                                    uint32_t* o0, uint32_t* o1) {
  uint32_t ks2 = k0 ^ k1 ^ 0x1BD11BDAu;
  x0 += k0; x1 += k1;
  const int ra[4] = {13, 15, 26, 6};
  const int rb[4] = {17, 29, 16, 24};
#pragma unroll
  for (int i = 0; i < 4; i++) { x0 += x1; x1 = rotl32(x1, ra[i]); x1 ^= x0; }
  x0 += k1; x1 += ks2 + 1u;
#pragma unroll
  for (int i = 0; i < 4; i++) { x0 += x1; x1 = rotl32(x1, rb[i]); x1 ^= x0; }
  x0 += ks2; x1 += k0 + 2u;
#pragma unroll
  for (int i = 0; i < 4; i++) { x0 += x1; x1 = rotl32(x1, ra[i]); x1 ^= x0; }
  x0 += k0; x1 += k1 + 3u;
#pragma unroll
  for (int i = 0; i < 4; i++) { x0 += x1; x1 = rotl32(x1, rb[i]); x1 ^= x0; }
  x0 += k1; x1 += ks2 + 4u;
#pragma unroll
  for (int i = 0; i < 4; i++) { x0 += x1; x1 = rotl32(x1, ra[i]); x1 ^= x0; }
  x0 += ks2; x1 += k0 + 5u;
  *o0 = x0; *o1 = x1;
}

__device__ inline float erfinv_xla_f32(float x) {
  float w = -log1pf(-x * x);
  float p;
  if (w < 5.0f) {
    w = w - 2.5f;
    p = 2.81022636e-08f;
    p = 3.43273939e-07f + p * w;
    p = -3.5233877e-06f + p * w;
    p = -4.39150654e-06f + p * w;
    p = 0.00021858087f + p * w;
    p = -0.00125372503f + p * w;
    p = -0.00417768164f + p * w;
    p = 0.246640727f + p * w;
    p = 1.50140941f + p * w;
  } else {
    w = sqrtf(w) - 3.0f;
    p = -0.000200214257f;
    p = 0.000100950558f + p * w;
    p = 0.00134934322f + p * w;
    p = -0.00367342844f + p * w;
    p = 0.00573950773f + p * w;
    p = -0.0076224613f + p * w;
    p = 0.00943887047f + p * w;
    p = 1.00167406f + p * w;
    p = 2.83297682f + p * w;
  }
  return p * x;
}

__device__ inline float jax_normal_from_bits(uint32_t bits) {
  float f = __uint_as_float((bits >> 9) | 0x3f800000u) - 1.0f;
  const float lo = -0.99999994f;  // nextafter(-1, 0)
  float u = f * (1.0f - lo) + lo;
  u = fmaxf(lo, u);
  return 1.4142135623730951f * erfinv_xla_f32(u);
}

__device__ inline float jax_normal_at(uint32_t ka, uint32_t kb, uint32_t i) {
  uint32_t o0, o1;
  threefry2x32(ka, kb, 0u, i, &o0, &o1);
  return jax_normal_from_bits(o0 ^ o1);
}

// ---------------- reductions (256 threads = 4 waves of 64) ----------------
__device__ inline double blockSum(double v, double* red, int tid) {
#pragma unroll
  for (int o = 32; o > 0; o >>= 1) v += __shfl_down(v, o, 64);
  __syncthreads();
  if ((tid & 63) == 0) red[tid >> 6] = v;
  __syncthreads();
  return (red[0] + red[1]) + (red[2] + red[3]);
}

__device__ inline double reduceS_sum(const double* arr, double* red, int tid) {
  __syncthreads();
  if (tid < 64) {
    double v = arr[tid] + arr[tid + 64] + arr[tid + 128];
#pragma unroll
    for (int o = 32; o > 0; o >>= 1) v += __shfl_down(v, o, 64);
    if (tid == 0) red[4] = v;
  }
  __syncthreads();
  return red[4];
}

__device__ inline double reduceS_min(const double* arr, double* red, int tid) {
  __syncthreads();
  if (tid < 64) {
    double v = fmin(arr[tid], fmin(arr[tid + 64], arr[tid + 128]));
#pragma unroll
    for (int o = 32; o > 0; o >>= 1) v = fmin(v, __shfl_down(v, o, 64));
    if (tid == 0) red[5] = v;
  }
  __syncthreads();
  return red[5];
}

// ---- wave-cooperative GEMV: dots[s] = sum_d x[d] * M[s*DD+d], s = 0..SS-1 ----
// Each wave owns 48 rows; per row, 64 lanes load float4 (coalesced 1KB) and
// tree-reduce via __shfl_down. 8 rows staged per batch (32 VGPR + 8 f64 acc).
__device__ inline void gemv_s(const double* __restrict__ x, const float* __restrict__ M,
                              double* __restrict__ dots, int tid) {
  const int wid = tid >> 6, lane = tid & 63;
  const double x0 = x[4 * lane + 0], x1 = x[4 * lane + 1];
  const double x2 = x[4 * lane + 2], x3 = x[4 * lane + 3];
  const float4* Mp = (const float4*)M + lane;
  const int r0 = wid * 48;
#pragma unroll 2
  for (int bq = 0; bq < 48; bq += 8) {
    const size_t base = (size_t)(r0 + bq) * 64;
    float4 f0 = Mp[base + 0 * 64];
    float4 f1 = Mp[base + 1 * 64];
    float4 f2 = Mp[base + 2 * 64];
    float4 f3 = Mp[base + 3 * 64];
    float4 f4 = Mp[base + 4 * 64];
    float4 f5 = Mp[base + 5 * 64];
    float4 f6 = Mp[base + 6 * 64];
    float4 f7 = Mp[base + 7 * 64];
    double a0 = x0*(double)f0.x + x1*(double)f0.y + x2*(double)f0.z + x3*(double)f0.w;
    double a1 = x0*(double)f1.x + x1*(double)f1.y + x2*(double)f1.z + x3*(double)f1.w;
    double a2 = x0*(double)f2.x + x1*(double)f2.y + x2*(double)f2.z + x3*(double)f2.w;
    double a3 = x0*(double)f3.x + x1*(double)f3.y + x2*(double)f3.z + x3*(double)f3.w;
    double a4 = x0*(double)f4.x + x1*(double)f4.y + x2*(double)f4.z + x3*(double)f4.w;
    double a5 = x0*(double)f5.x + x1*(double)f5.y + x2*(double)f5.z + x3*(double)f5.w;
    double a6 = x0*(double)f6.x + x1*(double)f6.y + x2*(double)f6.z + x3*(double)f6.w;
    double a7 = x0*(double)f7.x + x1*(double)f7.y + x2*(double)f7.z + x3*(double)f7.w;
#pragma unroll
    for (int o = 32; o > 0; o >>= 1) {
      a0 += __shfl_down(a0, o, 64);
      a1 += __shfl_down(a1, o, 64);
      a2 += __shfl_down(a2, o, 64);
      a3 += __shfl_down(a3, o, 64);
      a4 += __shfl_down(a4, o, 64);
      a5 += __shfl_down(a5, o, 64);
      a6 += __shfl_down(a6, o, 64);
      a7 += __shfl_down(a7, o, 64);
    }
    if (lane == 0) {
      dots[r0 + bq + 0] = a0; dots[r0 + bq + 1] = a1;
      dots[r0 + bq + 2] = a2; dots[r0 + bq + 3] = a3;
      dots[r0 + bq + 4] = a4; dots[r0 + bq + 5] = a5;
      dots[r0 + bq + 6] = a6; dots[r0 + bq + 7] = a7;
    }
  }
}

// d-mapped weighted sum over s, 16 scalar f32 loads staged, 8 f64 accs
#define DSUM(wArr, mat, outv) do {                                           \
    const float* mb_ = (mat);                                                \
    double s0_=0.0,s1_=0.0,s2_=0.0,s3_=0.0,s4_=0.0,s5_=0.0,s6_=0.0,s7_=0.0;  \
    for (int t0_ = 0; t0_ < SS; t0_ += 16) {                                 \
      float f0_ = mb_[(size_t)(t0_ + 0) * DD];                               \
      float f1_ = mb_[(size_t)(t0_ + 1) * DD];                               \
      float f2_ = mb_[(size_t)(t0_ + 2) * DD];                               \
      float f3_ = mb_[(size_t)(t0_ + 3) * DD];                               \
      float f4_ = mb_[(size_t)(t0_ + 4) * DD];                               \
      float f5_ = mb_[(size_t)(t0_ + 5) * DD];                               \
      float f6_ = mb_[(size_t)(t0_ + 6) * DD];                               \
      float f7_ = mb_[(size_t)(t0_ + 7) * DD];                               \
      float f8_ = mb_[(size_t)(t0_ + 8) * DD];                               \
      float f9_ = mb_[(size_t)(t0_ + 9) * DD];                               \
      float fa_ = mb_[(size_t)(t0_ + 10) * DD];                              \
      float fb_ = mb_[(size_t)(t0_ + 11) * DD];                              \
      float fc_ = mb_[(size_t)(t0_ + 12) * DD];                              \
      float fd_ = mb_[(size_t)(t0_ + 13) * DD];                              \
      float fe_ = mb_[(size_t)(t0_ + 14) * DD];                              \
      float ff_ = mb_[(size_t)(t0_ + 15) * DD];                              \
      s0_ += (wArr)[t0_ + 0] * (double)f0_;                                  \
      s1_ += (wArr)[t0_ + 1] * (double)f1_;                                  \
      s2_ += (wArr)[t0_ + 2] * (double)f2_;                                  \
      s3_ += (wArr)[t0_ + 3] * (double)f3_;                                  \
      s4_ += (wArr)[t0_ + 4] * (double)f4_;                                  \
      s5_ += (wArr)[t0_ + 5] * (double)f5_;                                  \
      s6_ += (wArr)[t0_ + 6] * (double)f6_;                                  \
      s7_ += (wArr)[t0_ + 7] * (double)f7_;                                  \
      s0_ += (wArr)[t0_ + 8] * (double)f8_;                                  \
      s1_ += (wArr)[t0_ + 9] * (double)f9_;                                  \
      s2_ += (wArr)[t0_ + 10] * (double)fa_;                                 \
      s3_ += (wArr)[t0_ + 11] * (double)fb_;                                 \
      s4_ += (wArr)[t0_ + 12] * (double)fc_;                                 \
      s5_ += (wArr)[t0_ + 13] * (double)fd_;                                 \
      s6_ += (wArr)[t0_ + 14] * (double)fe_;                                 \
      s7_ += (wArr)[t0_ + 15] * (double)ff_;                                 \
    }                                                                        \
    (outv) = ((s0_ + s1_) + (s2_ + s3_)) + ((s4_ + s5_) + (s6_ + s7_));      \
  } while (0)

// ---------------- W transpose ----------------
__global__ void transpose4(const float* __restrict__ Wq, const float* __restrict__ Wk,
                           const float* __restrict__ Wv, const float* __restrict__ Wo,
                           float* __restrict__ WqT, float* __restrict__ WkT,
                           float* __restrict__ WvT, float* __restrict__ WoT) {
  int m = blockIdx.x >> 8;
  int i = blockIdx.x & 255;
  int j = threadIdx.x;
  const float* S_; float* D_;
  if (m == 0) { S_ = Wq; D_ = WqT; }
  else if (m == 1) { S_ = Wk; D_ = WkT; }
  else if (m == 2) { S_ = Wv; D_ = WvT; }
  else { S_ = Wo; D_ = WoT; }
  D_[i * DD + j] = S_[j * DD + i];
}

// dot of xs[LDS f32, len DD] with WT column j, 8 named f64 accumulators (round-4)
__device__ inline double colDot(const float* __restrict__ xs,
                                const float* __restrict__ WT, int j) {
  const float* cb = WT + j;
  double s0=0.0,s1=0.0,s2=0.0,s3=0.0,s4=0.0,s5=0.0,s6=0.0,s7=0.0;
  for (int i0 = 0; i0 < DD; i0 += 8) {
    float f0 = cb[(size_t)(i0 + 0) * DD];
    float f1 = cb[(size_t)(i0 + 1) * DD];
    float f2 = cb[(size_t)(i0 + 2) * DD];
    float f3 = cb[(size_t)(i0 + 3) * DD];
    float f4 = cb[(size_t)(i0 + 4) * DD];
    float f5 = cb[(size_t)(i0 + 5) * DD];
    float f6 = cb[(size_t)(i0 + 6) * DD];
    float f7 = cb[(size_t)(i0 + 7) * DD];
    s0 += (double)xs[i0 + 0] * (double)f0;
    s1 += (double)xs[i0 + 1] * (double)f1;
    s2 += (double)xs[i0 + 2] * (double)f2;
    s3 += (double)xs[i0 + 3] * (double)f3;
    s4 += (double)xs[i0 + 4] * (double)f4;
    s5 += (double)xs[i0 + 5] * (double)f5;
    s6 += (double)xs[i0 + 6] * (double)f6;
    s7 += (double)xs[i0 + 7] * (double)f7;
  }
  return ((s0 + s1) + (s2 + s3)) + ((s4 + s5) + (s6 + s7));
}

// ---------------- fused QKV projection + expmap0 rows (round-4, no khT) ----------------
__global__ __launch_bounds__(256) void proj_kernel(
    const float* __restrict__ q_in, const float* __restrict__ k_in, const float* __restrict__ v_in,
    const float* __restrict__ WqT, const float* __restrict__ WkT, const float* __restrict__ WvT,
    const float* __restrict__ bq, const float* __restrict__ bk, const float* __restrict__ bv,
    float* __restrict__ qh, float* __restrict__ kb, float* __restrict__ vb,
    float* __restrict__ kh, double* __restrict__ y2g) {
  const int row = blockIdx.x, m = blockIdx.y, j = threadIdx.x;
  __shared__ float xs[DD];
  __shared__ double red[8];
  const float* x; const float* WT; const float* bias;
  if (m == 0) { x = q_in; WT = WqT; bias = bq; }
  else if (m == 1) { x = k_in; WT = WkT; bias = bk; }
  else { x = v_in; WT = WvT; bias = bv; }
  xs[j] = x[(size_t)row * DD + j];
  __syncthreads();
  double val = colDot(xs, WT, j) + (double)bias[j];

  if (m == 2) { vb[(size_t)row * DD + j] = (float)val; return; }

  double n2 = blockSum(val * val, red, j);
  double n = sqrt(n2);
  double cf = fmin(4.0 / (n + 1e-8), 1.0);
  double ncl = fmax(n * cf, 1e-15);
  double sc = tanh(ncl) * cf / ncl;
  if (m == 0) {
    qh[(size_t)row * DD + j] = (float)(val * sc);
  } else {
    kb[(size_t)row * DD + j] = (float)val;
    float khf = (float)(val * sc);
    kh[(size_t)row * DD + j] = khf;
    double y2 = blockSum((double)khf * (double)khf, red, j);
    if (j == 0) y2g[row] = y2;
  }
}

// ---------------- main fused per-(b,q) kernel ----------------
__global__ __launch_bounds__(256) void resonance_main(
    const float* __restrict__ q_hyp, const float* __restrict__ k_hyp,
    const float* __restrict__ kmat, const float* __restrict__ vmat,
    const double* __restrict__ y2g,
    const float* __restrict__ WoT, const float* __restrict__ bo,
    const float* __restrict__ tau_p, const float* __restrict__ ts_p,
    float* __restrict__ out) {
  __shared__ __align__(16) double xq[DD], xc[DD], vr[DD];
  __shared__ double y2s[SS], wun[SS], wns[SS], alf[SS], bet[SS], sA[SS], sB[SS], dots[SS];
  __shared__ __align__(16) float hfl[DD];
  __shared__ double red[8];
  const int tid = threadIdx.x;
  const int blk = blockIdx.x;
  const int b = blk / SS;
  const size_t rowOff = (size_t)blk * DD;
  const float* khB = k_hyp + (size_t)b * SS * DD;
  const float* kB = kmat + (size_t)b * SS * DD;
  const float* vB = vmat + (size_t)b * SS * DD;

  // inline JAX PRNG: nk = split(key(42), 3), partitionable scheme
  uint32_t nk0a, nk0b, nk1a, nk1b, nk2a, nk2b;
  threefry2x32(0u, 42u, 0u, 0u, &nk0a, &nk0b);
  threefry2x32(0u, 42u, 0u, 1u, &nk1a, &nk1b);
  threefry2x32(0u, 42u, 0u, 2u, &nk2a, &nk2b);
  const uint32_t ei = (uint32_t)(rowOff + tid);
  const double noiseval = 1e-5 * (double)jax_normal_at(nk0a, nk0b, ei);
  const double vrndval = (double)jax_normal_at(nk1a, nk1b, ei);
  const double odeval = 1e-4 * (double)jax_normal_at(nk2a, nk2b, (uint32_t)blk);

  double xqv = (double)q_hyp[rowOff + tid];
  xq[tid] = xqv;
  if (tid < SS) y2s[tid] = y2g[b * SS + tid];
  double x2q = blockSum(xqv * xqv, red, tid);  // syncs cover xq/y2s writes

  // ---- pairwise hyperbolic distance row (wave-cooperative GEMV) ----
  gemv_s(xq, khB, dots, tid);
  __syncthreads();
  if (tid < SS) {
    double dot = dots[tid];
    double y2 = y2s[tid];
    double A = 1.0 - 2.0 * dot + y2;
    double Dn = fmax(1.0 - 2.0 * dot + x2q * y2, 1e-15);
    double Bc = 1.0 - x2q;
    double u2 = (A * A * x2q - 2.0 * A * Bc * dot + Bc * Bc * y2) / (Dn * Dn);
    double unr = sqrt(fmax(u2, 0.0));
    sA[tid] = 2.0 * atanh(fmin(unr, 1.0 - 1e-7));
  }
  double mind = reduceS_min(sA, red, tid);
  if (tid < SS) wun[tid] = exp(-(sA[tid] - mind));
  double wsum = reduceS_sum(wun, red, tid);
  if (tid < SS) wns[tid] = wun[tid] * (1.0 / (wsum + 1e-8));
  __syncthreads();

  // ---- fused: h = wns.v and mu_raw = wns.k (16 loads staged) ----
  double hreg, mu;
  {
    const float* vb_ = vB + tid;
    const float* kb_ = kB + tid;
    double h0=0.0,h1=0.0,h2=0.0,h3=0.0, m0=0.0,m1=0.0,m2=0.0,m3=0.0;
    for (int s0 = 0; s0 < SS; s0 += 8) {
      float v0 = vb_[(size_t)(s0 + 0) * DD];
      float v1 = vb_[(size_t)(s0 + 1) * DD];
      float v2 = vb_[(size_t)(s0 + 2) * DD];
      float v3 = vb_[(size_t)(s0 + 3) * DD];
      float v4 = vb_[(size_t)(s0 + 4) * DD];
      float v5 = vb_[(size_t)(s0 + 5) * DD];
      float v6 = vb_[(size_t)(s0 + 6) * DD];
      float v7 = vb_[(size_t)(s0 + 7) * DD];
      float k0 = kb_[(size_t)(s0 + 0) * DD];
      float k1 = kb_[(size_t)(s0 + 1) * DD];
      float k2 = kb_[(size_t)(s0 + 2) * DD];
      float k3 = kb_[(size_t)(s0 + 3) * DD];
      float k4 = kb_[(size_t)(s0 + 4) * DD];
      float k5 = kb_[(size_t)(s0 + 5) * DD];
      float k6 = kb_[(size_t)(s0 + 6) * DD];
      float k7 = kb_[(size_t)(s0 + 7) * DD];
      double w0 = wns[s0 + 0], w1 = wns[s0 + 1], w2 = wns[s0 + 2], w3 = wns[s0 + 3];
      double w4 = wns[s0 + 4], w5 = wns[s0 + 5], w6 = wns[s0 + 6], w7 = wns[s0 + 7];
      h0 += w0 * (double)v0; m0 += w0 * (double)k0;
      h1 += w1 * (double)v1; m1 += w1 * (double)k1;
      h2 += w2 * (double)v2; m2 += w2 * (double)k2;
      h3 += w3 * (double)v3; m3 += w3 * (double)k3;
      h0 += w4 * (double)v4; m0 += w4 * (double)k4;
      h1 += w5 * (double)v5; m1 += w5 * (double)k5;
      h2 += w6 * (double)v6; m2 += w6 * (double)k6;
      h3 += w7 * (double)v7; m3 += w7 * (double)k7;
    }
    hreg = (h0 + h1) + (h2 + h3);
    mu = (m0 + m1) + (m2 + m3);
  }

  // ---- mu0 = expmap0(clip_tangent(mu)) ----
  double x2c;
  {
    double n2 = blockSum(mu * mu, red, tid);
    double n = sqrt(n2);
    double cf = fmin(4.0 / (n + 1e-8), 1.0);
    double ncl = fmax(n * cf, 1e-15);
    double th = tanh(ncl);
    xc[tid] = mu * (th * cf / ncl);
    x2c = th * th;
  }
  __syncthreads();

  // ---- Karcher flow: 3 Riemannian SGD steps ----
  for (int it = 0; it < 3; ++it) {
    gemv_s(xc, khB, dots, tid);
    __syncthreads();
    if (tid < SS) {
      double dot = dots[tid];
      double y2 = y2s[tid];
      double A = 1.0 - 2.0 * dot + y2;
      double Dn = fmax(1.0 - 2.0 * dot + x2c * y2, 1e-15);
      double Bc = 1.0 - x2c;
      double u2 = (A * A * x2c - 2.0 * A * Bc * dot + Bc * Bc * y2) / (Dn * Dn);
      double unr = sqrt(fmax(u2, 0.0));
      double un = fmax(unr, 1e-15);
      double coef = fmax(Bc, 1e-15) * atanh(fmin(un, 1.0 - 1e-7)) / un;
      double cs = wns[tid] * coef / Dn;
      sA[tid] = cs;
      sB[tid] = cs * A;
    }
    double S1 = reduceS_sum(sB, red, tid);   // syncs cover sA/sB writes
    double g;
    DSUM(sA, khB + tid, g);
    double xold = xc[tid];
    double Bc = 1.0 - x2c;
    double vg = Bc * g - S1 * xold;           // v_grad[d]
    double nv2 = blockSum(vg * vg, red, tid);
    double nv = 0.1 * sqrt(nv2);
    double cf = fmin(4.0 / (nv + 1e-8), 1.0);
    double nw = fmax(nv * cf, 1e-15);
    double tsc = tanh(nw / fmax(Bc, 1e-15));
    double zco = tsc * 0.1 * cf / nw;
    double z = zco * vg;
    double xz = blockSum(xold * z, red, tid);
    double z2 = tsc * tsc;
    double den = fmax(1.0 + 2.0 * xz + x2c * z2, 1e-15);
    double xnew = ((1.0 + 2.0 * xz + z2) * xold + (1.0 - x2c) * z) / den;
    xc[tid] = xnew;
    x2c = blockSum(xnew * xnew, red, tid);    // syncs cover xc write
  }

  // ---- k_centroid = projx(mu + noise) ----
  {
    double cn = xc[tid] + noiseval;
    double n2 = blockSum(cn * cn, red, tid);
    double nn = sqrt(n2);
    if (nn > 1.0 - 1e-5) cn *= (1.0 - 1e-5) / fmax(nn, 1e-15);
    xc[tid] = cn;
    x2c = blockSum(cn * cn, red, tid);        // syncs cover xc write
  }

  // ---- c2k distances, entropy, variance; alf/bet for weighted_k ----
  gemv_s(xc, khB, dots, tid);
  __syncthreads();
  if (tid < SS) {
    double dot = dots[tid];
    double y2 = y2s[tid];
    double A = 1.0 - 2.0 * dot + y2;
    double Dn = fmax(1.0 - 2.0 * dot + x2c * y2, 1e-15);
    double Bc = 1.0 - x2c;
    double u2 = (A * A * x2c - 2.0 * A * Bc * dot + Bc * Bc * y2) / (Dn * Dn);
    double unr = sqrt(fmax(u2, 0.0));
    double c2k = 2.0 * atanh(fmin(unr, 1.0 - 1e-7));
    sA[tid] = wns[tid] * c2k * c2k;
    sB[tid] = -wns[tid] * log(wns[tid] + 1e-8);
    double un = fmax(unr, 1e-15);
    double gl = fmax(Bc, 1e-15) * atanh(fmin(un, 1.0 - 1e-7)) / (un * Dn);
    double sq = sqrt(wun[tid] + 1e-8);
    alf[tid] = -sq * gl * A;
    bet[tid] = sq * gl * Bc;
  }
  double variance = reduceS_sum(sA, red, tid);
  double entropy = reduceS_sum(sB, red, tid);
  double tau = (double)tau_p[0];
  double tension = variance - tau * exp(entropy);

  // ---- power iteration on weighted_k (rank-structured) ----
  {
    double n2 = blockSum(vrndval * vrndval, red, tid);
    vr[tid] = vrndval / fmax(sqrt(n2), 1e-8);
  }
  for (int it = 0; it < 3; ++it) {
    double dxv = blockSum(xc[tid] * vr[tid], red, tid);  // syncs cover vr write
    gemv_s(vr, khB, dots, tid);
    __syncthreads();
    if (tid < SS) {
      double pj = alf[tid] * dxv + bet[tid] * dots[tid];
      sA[tid] = alf[tid] * pj;
      sB[tid] = bet[tid] * pj;
    }
    double T1 = reduceS_sum(sA, red, tid);
    double g;
    DSUM(sB, khB + tid, g);
    double vnew = T1 * xc[tid] + g;
    double n2 = blockSum(vnew * vnew, red, tid);
    vr[tid] = vnew / fmax(sqrt(n2), 1e-8);
  }

  // ---- w_proj ----
  double wproj;
  {
    double wg = vr[tid] / fmax(1.0 - x2c, 1e-15);
    double nq = fmax(sqrt(x2q), 1e-15);
    double aq = atanh(fmin(nq, 1.0 - 1e-7)) / nq;
    double nc = fmax(sqrt(x2c), 1e-15);
    double ac = atanh(fmin(nc, 1.0 - 1e-7)) / nc;
    double f = aq * xq[tid] - ac * xc[tid];
    double n2 = blockSum(f * f, red, tid);
    double fb = f / fmax(sqrt(n2), 1e-8);
    wproj = (variance > 1e-5) ? wg : fb;
  }

  // ---- h_comp, x, pitchfork RK4 ----
  double hn2 = blockSum(hreg * hreg, red, tid);
  double hn = sqrt(hn2);
  double hsc = asinh(hn) / (hn + 1e-8);
  double hc = hsc * hreg;
  double x = blockSum(hc * wproj, red, tid);
  double xi = (x == 0.0) ? odeval : x;
  const double dt = 0.5;
#pragma unroll
  for (int r = 0; r < 4; ++r) {
    double k1 = dt * (tension * xi - xi * xi * xi);
    double a2 = xi + 0.5 * k1;
    double k2 = dt * (tension * a2 - a2 * a2 * a2);
    double a3 = xi + 0.5 * k2;
    double k3 = dt * (tension * a3 - a3 * a3 * a3);
    double a4 = xi + k3;
    double k4 = dt * (tension * a4 - a4 * a4 * a4);
    xi += (k1 + 2.0 * k2 + 2.0 * k3 + k4) / 6.0;
  }
  double ts = (double)ts_p[0];
  double hp = (hc + (xi - x) * wproj) * ts;
  double hp2 = blockSum(hp * hp, red, tid);
  double nhp = sqrt(hp2);
  double cf = fmin(4.0 / (nhp + 1e-8), 1.0);
  double ncl = fmax(nhp * cf, 1e-15);
  double th = tanh(ncl);
  double nb = fmax(th, 1e-15);
  double ab = atanh(fmin(nb, 1.0 - 1e-7)) / nb;
  double hob = ab * th * cf / ncl * hp;
  double gate = fmax(tanh(tension / fmax(tau, 1e-3)), 0.0);

  // ---- fused output GEMM (coalesced WoT columns) ----
  hfl[tid] = (float)((1.0 - gate) * hreg + gate * hob);
  __syncthreads();
  double o = colDot(hfl, WoT, tid) + (double)bo[tid];
  out[rowOff + tid] = (float)o;
}

// ---------------- launch ----------------
extern "C" void kernel_launch(void* const* d_in, const int* in_sizes, int n_in,
                              void* d_out, int out_size, void* d_ws, size_t ws_size,
                              hipStream_t stream) {
  const float* q_in = (const float*)d_in[0];
  const float* k_in = (const float*)d_in[1];
  const float* v_in = (const float*)d_in[2];
  const float* Wq = (const float*)d_in[3];
  const float* bq = (const float*)d_in[4];
  const float* Wk = (const float*)d_in[5];
  const float* bk = (const float*)d_in[6];
  const float* Wv = (const float*)d_in[7];
  const float* bv = (const float*)d_in[8];
  const float* Wo = (const float*)d_in[9];
  const float* bo = (const float*)d_in[10];
  const float* tau = (const float*)d_in[11];
  const float* ts = (const float*)d_in[12];
  float* out = (float*)d_out;
  (void)in_sizes; (void)n_in; (void)out_size; (void)ws_size;

  char* base = (char*)d_ws;
  size_t off = 0;
  auto alloc = [&](size_t bytes) -> void* {
    void* p = base + off;
    off += (bytes + 255) & ~(size_t)255;
    return p;
  };
  float* WqT = (float*)alloc((size_t)DD * DD * 4);
  float* WkT = (float*)alloc((size_t)DD * DD * 4);
  float* WvT = (float*)alloc((size_t)DD * DD * 4);
  float* WoT = (float*)alloc((size_t)DD * DD * 4);
  float* kb = (float*)alloc((size_t)NE * 4);
  float* vb = (float*)alloc((size_t)NE * 4);
  float* qh = (float*)alloc((size_t)NE * 4);
  float* kh = (float*)alloc((size_t)NE * 4);
  double* y2g = (double*)alloc((size_t)NROW * 8);

  hipLaunchKernelGGL(transpose4, dim3(4 * DD), dim3(DD), 0, stream,
                     Wq, Wk, Wv, Wo, WqT, WkT, WvT, WoT);
  hipLaunchKernelGGL(proj_kernel, dim3(NROW, 3), dim3(DD), 0, stream,
                     q_in, k_in, v_in, WqT, WkT, WvT, bq, bk, bv,
                     qh, kb, vb, kh, y2g);
  hipLaunchKernelGGL(resonance_main, dim3(NROW), dim3(DD), 0, stream,
                     qh, kh, kb, vb, y2g, WoT, bo, tau, ts, out);
}

// Round 9
// 144.316 us; speedup vs baseline: 5.7727x; 1.3398x over previous
//
#include <hip/hip_runtime.h>
#include <hip/hip_bf16.h>
#include <stdint.h>

#define BB 2
#define SS 192
#define DD 256
#define NROW (BB * SS)   // 384
#define NE (NROW * DD)   // 98304

// ---------------- threefry2x32-20 (Random123 / JAX, partitionable) ----------------
__device__ __forceinline__ uint32_t rotl32(uint32_t v, int d) {
  return (v << d) | (v >> (32 - d));
}

__device__ inline void threefry2x32(uint32_t k0, uint32_t k1, uint32_t x0, uint32_t x1,
                                    uint32_t* o0, uint32_t* o1) {
  uint32_t ks2 = k0 ^ k1 ^ 0x1BD11BDAu;
  x0 += k0; x1 += k1;
  const int ra[4] = {13, 15, 26, 6};
  const int rb[4] = {17, 29, 16, 24};
#pragma unroll
  for (int i = 0; i < 4; i++) { x0 += x1; x1 = rotl32(x1, ra[i]); x1 ^= x0; }
  x0 += k1; x1 += ks2 + 1u;
#pragma unroll
  for (int i = 0; i < 4; i++) { x0 += x1; x1 = rotl32(x1, rb[i]); x1 ^= x0; }
  x0 += ks2; x1 += k0 + 2u;
#pragma unroll
  for (int i = 0; i < 4; i++) { x0 += x1; x1 = rotl32(x1, ra[i]); x1 ^= x0; }
  x0 += k0; x1 += k1 + 3u;
#pragma unroll
  for (int i = 0; i < 4; i++) { x0 += x1; x1 = rotl32(x1, rb[i]); x1 ^= x0; }
  x0 += k1; x1 += ks2 + 4u;
#pragma unroll
  for (int i = 0; i < 4; i++) { x0 += x1; x1 = rotl32(x1, ra[i]); x1 ^= x0; }
  x0 += ks2; x1 += k0 + 5u;
  *o0 = x0; *o1 = x1;
}

__device__ inline float erfinv_xla_f32(float x) {
  float w = -log1pf(-x * x);
  float p;
  if (w < 5.0f) {
    w = w - 2.5f;
    p = 2.81022636e-08f;
    p = 3.43273939e-07f + p * w;
    p = -3.5233877e-06f + p * w;
    p = -4.39150654e-06f + p * w;
    p = 0.00021858087f + p * w;
    p = -0.00125372503f + p * w;
    p = -0.00417768164f + p * w;
    p = 0.246640727f + p * w;
    p = 1.50140941f + p * w;
  } else {
    w = sqrtf(w) - 3.0f;
    p = -0.000200214257f;
    p = 0.000100950558f + p * w;
    p = 0.00134934322f + p * w;
    p = -0.00367342844f + p * w;
    p = 0.00573950773f + p * w;
    p = -0.0076224613f + p * w;
    p = 0.00943887047f + p * w;
    p = 1.00167406f + p * w;
    p = 2.83297682f + p * w;
  }
  return p * x;
}

__device__ inline float jax_normal_from_bits(uint32_t bits) {
  float f = __uint_as_float((bits >> 9) | 0x3f800000u) - 1.0f;
  const float lo = -0.99999994f;  // nextafter(-1, 0)
  float u = f * (1.0f - lo) + lo;
  u = fmaxf(lo, u);
  return 1.4142135623730951f * erfinv_xla_f32(u);
}

__device__ inline float jax_normal_at(uint32_t ka, uint32_t kb, uint32_t i) {
  uint32_t o0, o1;
  threefry2x32(ka, kb, 0u, i, &o0, &o1);
  return jax_normal_from_bits(o0 ^ o1);
}

// ---------------- reductions (256 threads = 4 waves of 64) ----------------
__device__ inline double blockSum(double v, double* red, int tid) {
#pragma unroll
  for (int o = 32; o > 0; o >>= 1) v += __shfl_down(v, o, 64);
  __syncthreads();
  if ((tid & 63) == 0) red[tid >> 6] = v;
  __syncthreads();
  return (red[0] + red[1]) + (red[2] + red[3]);
}

__device__ inline double reduceS_sum(const double* arr, double* red, int tid) {
  __syncthreads();
  if (tid < 64) {
    double v = arr[tid] + arr[tid + 64] + arr[tid + 128];
#pragma unroll
    for (int o = 32; o > 0; o >>= 1) v += __shfl_down(v, o, 64);
    if (tid == 0) red[4] = v;
  }
  __syncthreads();
  return red[4];
}

__device__ inline double reduceS_min(const double* arr, double* red, int tid) {
  __syncthreads();
  if (tid < 64) {
    double v = fmin(arr[tid], fmin(arr[tid + 64], arr[tid + 128]));
#pragma unroll
    for (int o = 32; o > 0; o >>= 1) v = fmin(v, __shfl_down(v, o, 64));
    if (tid == 0) red[5] = v;
  }
  __syncthreads();
  return red[5];
}

// per-s dot over d (tid < SS): 8 NAMED f64 accumulators, loads staged in named floats
#define SDOT(vecLds, khTp, outv) do {                                        \
    const float* cb_ = (khTp) + tid;                                         \
    double s0_=0.0,s1_=0.0,s2_=0.0,s3_=0.0,s4_=0.0,s5_=0.0,s6_=0.0,s7_=0.0;  \
    for (int d0_ = 0; d0_ < DD; d0_ += 8) {                                  \
      float f0_ = cb_[(size_t)(d0_ + 0) * SS];                               \
      float f1_ = cb_[(size_t)(d0_ + 1) * SS];                               \
      float f2_ = cb_[(size_t)(d0_ + 2) * SS];                               \
      float f3_ = cb_[(size_t)(d0_ + 3) * SS];                               \
      float f4_ = cb_[(size_t)(d0_ + 4) * SS];                               \
      float f5_ = cb_[(size_t)(d0_ + 5) * SS];                               \
      float f6_ = cb_[(size_t)(d0_ + 6) * SS];                               \
      float f7_ = cb_[(size_t)(d0_ + 7) * SS];                               \
      s0_ += (vecLds)[d0_ + 0] * (double)f0_;                                \
      s1_ += (vecLds)[d0_ + 1] * (double)f1_;                                \
      s2_ += (vecLds)[d0_ + 2] * (double)f2_;                                \
      s3_ += (vecLds)[d0_ + 3] * (double)f3_;                                \
      s4_ += (vecLds)[d0_ + 4] * (double)f4_;                                \
      s5_ += (vecLds)[d0_ + 5] * (double)f5_;                                \
      s6_ += (vecLds)[d0_ + 6] * (double)f6_;                                \
      s7_ += (vecLds)[d0_ + 7] * (double)f7_;                                \
    }                                                                        \
    (outv) = ((s0_ + s1_) + (s2_ + s3_)) + ((s4_ + s5_) + (s6_ + s7_));      \
  } while (0)

// d-mapped weighted sum over s: sum_s wArr[s] * mat[s*DD + tid]
#define DSUM(wArr, mat, outv) do {                                           \
    const float* mb_ = (mat) + tid;                                          \
    double s0_=0.0,s1_=0.0,s2_=0.0,s3_=0.0,s4_=0.0,s5_=0.0,s6_=0.0,s7_=0.0;  \
    for (int t0_ = 0; t0_ < SS; t0_ += 8) {                                  \
      float f0_ = mb_[(size_t)(t0_ + 0) * DD];                               \
      float f1_ = mb_[(size_t)(t0_ + 1) * DD];                               \
      float f2_ = mb_[(size_t)(t0_ + 2) * DD];                               \
      float f3_ = mb_[(size_t)(t0_ + 3) * DD];                               \
      float f4_ = mb_[(size_t)(t0_ + 4) * DD];                               \
      float f5_ = mb_[(size_t)(t0_ + 5) * DD];                               \
      float f6_ = mb_[(size_t)(t0_ + 6) * DD];                               \
      float f7_ = mb_[(size_t)(t0_ + 7) * DD];                               \
      s0_ += (wArr)[t0_ + 0] * (double)f0_;                                  \
      s1_ += (wArr)[t0_ + 1] * (double)f1_;                                  \
      s2_ += (wArr)[t0_ + 2] * (double)f2_;                                  \
      s3_ += (wArr)[t0_ + 3] * (double)f3_;                                  \
      s4_ += (wArr)[t0_ + 4] * (double)f4_;                                  \
      s5_ += (wArr)[t0_ + 5] * (double)f5_;                                  \
      s6_ += (wArr)[t0_ + 6] * (double)f6_;                                  \
      s7_ += (wArr)[t0_ + 7] * (double)f7_;                                  \
    }                                                                        \
    (outv) = ((s0_ + s1_) + (s2_ + s3_)) + ((s4_ + s5_) + (s6_ + s7_));      \
  } while (0)

// ---------------- W transpose ----------------
__global__ void transpose4(const float* __restrict__ Wq, const float* __restrict__ Wk,
                           const float* __restrict__ Wv, const float* __restrict__ Wo,
                           float* __restrict__ WqT, float* __restrict__ WkT,
                           float* __restrict__ WvT, float* __restrict__ WoT) {
  int m = blockIdx.x >> 8;
  int i = blockIdx.x & 255;
  int j = threadIdx.x;
  const float* S_; float* D_;
  if (m == 0) { S_ = Wq; D_ = WqT; }
  else if (m == 1) { S_ = Wk; D_ = WkT; }
  else if (m == 2) { S_ = Wv; D_ = WvT; }
  else { S_ = Wo; D_ = WoT; }
  D_[i * DD + j] = S_[j * DD + i];
}

// dot of xs[LDS f32, len DD] with WT column j, 8 named f64 accumulators
__device__ inline double colDot(const float* __restrict__ xs,
                                const float* __restrict__ WT, int j) {
  const float* cb = WT + j;
  double s0=0.0,s1=0.0,s2=0.0,s3=0.0,s4=0.0,s5=0.0,s6=0.0,s7=0.0;
  for (int i0 = 0; i0 < DD; i0 += 8) {
    float f0 = cb[(size_t)(i0 + 0) * DD];
    float f1 = cb[(size_t)(i0 + 1) * DD];
    float f2 = cb[(size_t)(i0 + 2) * DD];
    float f3 = cb[(size_t)(i0 + 3) * DD];
    float f4 = cb[(size_t)(i0 + 4) * DD];
    float f5 = cb[(size_t)(i0 + 5) * DD];
    float f6 = cb[(size_t)(i0 + 6) * DD];
    float f7 = cb[(size_t)(i0 + 7) * DD];
    s0 += (double)xs[i0 + 0] * (double)f0;
    s1 += (double)xs[i0 + 1] * (double)f1;
    s2 += (double)xs[i0 + 2] * (double)f2;
    s3 += (double)xs[i0 + 3] * (double)f3;
    s4 += (double)xs[i0 + 4] * (double)f4;
    s5 += (double)xs[i0 + 5] * (double)f5;
    s6 += (double)xs[i0 + 6] * (double)f6;
    s7 += (double)xs[i0 + 7] * (double)f7;
  }
  return ((s0 + s1) + (s2 + s3)) + ((s4 + s5) + (s6 + s7));
}

// ---------------- fused QKV projection + expmap0 rows (round-4 exact) ----------------
__global__ __launch_bounds__(256) void proj_kernel(
    const float* __restrict__ q_in, const float* __restrict__ k_in, const float* __restrict__ v_in,
    const float* __restrict__ WqT, const float* __restrict__ WkT, const float* __restrict__ WvT,
    const float* __restrict__ bq, const float* __restrict__ bk, const float* __restrict__ bv,
    float* __restrict__ qh, float* __restrict__ kb, float* __restrict__ vb,
    float* __restrict__ kh, float* __restrict__ khT, double* __restrict__ y2g) {
  const int row = blockIdx.x, m = blockIdx.y, j = threadIdx.x;
  __shared__ float xs[DD];
  __shared__ double red[8];
  const float* x; const float* WT; const float* bias;
  if (m == 0) { x = q_in; WT = WqT; bias = bq; }
  else if (m == 1) { x = k_in; WT = WkT; bias = bk; }
  else { x = v_in; WT = WvT; bias = bv; }
  xs[j] = x[(size_t)row * DD + j];
  __syncthreads();
  double val = colDot(xs, WT, j) + (double)bias[j];

  if (m == 2) { vb[(size_t)row * DD + j] = (float)val; return; }

  double n2 = blockSum(val * val, red, j);
  double n = sqrt(n2);
  double cf = fmin(4.0 / (n + 1e-8), 1.0);
  double ncl = fmax(n * cf, 1e-15);
  double sc = tanh(ncl) * cf / ncl;
  if (m == 0) {
    qh[(size_t)row * DD + j] = (float)(val * sc);
  } else {
    kb[(size_t)row * DD + j] = (float)val;
    float khf = (float)(val * sc);
    kh[(size_t)row * DD + j] = khf;
    int bb = row / SS, s = row % SS;
    khT[((size_t)bb * DD + j) * SS + s] = khf;
    double y2 = blockSum((double)khf * (double)khf, red, j);
    if (j == 0) y2g[row] = y2;
  }
}

// ---------------- main fused per-(b,q) kernel (round-4 + fused output GEMM) ----------------
__global__ __launch_bounds__(256) void resonance_main(
    const float* __restrict__ q_hyp, const float* __restrict__ k_hyp,
    const float* __restrict__ k_hypT, const float* __restrict__ kmat,
    const float* __restrict__ vmat, const double* __restrict__ y2g,
    const float* __restrict__ WoT, const float* __restrict__ bo,
    const float* __restrict__ tau_p, const float* __restrict__ ts_p,
    float* __restrict__ out) {
  __shared__ double xq[DD], xc[DD], vr[DD];
  __shared__ double y2s[SS], wun[SS], wns[SS], alf[SS], bet[SS], sA[SS], sB[SS];
  __shared__ float hfl[DD];
  __shared__ double red[8];
  const int tid = threadIdx.x;
  const int blk = blockIdx.x;
  const int b = blk / SS;
  const size_t rowOff = (size_t)blk * DD;
  const float* khB = k_hyp + (size_t)b * SS * DD;
  const float* khT = k_hypT + (size_t)b * DD * SS;
  const float* kB = kmat + (size_t)b * SS * DD;
  const float* vB = vmat + (size_t)b * SS * DD;

  // inline JAX PRNG: nk = split(key(42), 3), partitionable scheme
  uint32_t nk0a, nk0b, nk1a, nk1b, nk2a, nk2b;
  threefry2x32(0u, 42u, 0u, 0u, &nk0a, &nk0b);
  threefry2x32(0u, 42u, 0u, 1u, &nk1a, &nk1b);
  threefry2x32(0u, 42u, 0u, 2u, &nk2a, &nk2b);
  const uint32_t ei = (uint32_t)(rowOff + tid);
  const double noiseval = 1e-5 * (double)jax_normal_at(nk0a, nk0b, ei);
  const double vrndval = (double)jax_normal_at(nk1a, nk1b, ei);
  const double odeval = 1e-4 * (double)jax_normal_at(nk2a, nk2b, (uint32_t)blk);

  double xqv = (double)q_hyp[rowOff + tid];
  xq[tid] = xqv;
  if (tid < SS) y2s[tid] = y2g[b * SS + tid];
  double x2q = blockSum(xqv * xqv, red, tid);  // syncs cover xq/y2s writes

  // ---- pairwise hyperbolic distance row ----
  if (tid < SS) {
    double dot;
    SDOT(xq, khT, dot);
    double y2 = y2s[tid];
    double A = 1.0 - 2.0 * dot + y2;
    double Dn = fmax(1.0 - 2.0 * dot + x2q * y2, 1e-15);
    double Bc = 1.0 - x2q;
    double u2 = (A * A * x2q - 2.0 * A * Bc * dot + Bc * Bc * y2) / (Dn * Dn);
    double unr = sqrt(fmax(u2, 0.0));
    sA[tid] = 2.0 * atanh(fmin(unr, 1.0 - 1e-7));
  }
  double mind = reduceS_min(sA, red, tid);
  if (tid < SS) wun[tid] = exp(-(sA[tid] - mind));
  double wsum = reduceS_sum(wun, red, tid);
  if (tid < SS) wns[tid] = wun[tid] * (1.0 / (wsum + 1e-8));
  __syncthreads();

  // ---- fused: h = wns.v and mu_raw = wns.k (4+4 named accumulators) ----
  double hreg, mu;
  {
    const float* vb_ = vB + tid;
    const float* kb_ = kB + tid;
    double h0=0.0,h1=0.0,h2=0.0,h3=0.0, m0=0.0,m1=0.0,m2=0.0,m3=0.0;
    for (int s0 = 0; s0 < SS; s0 += 4) {
      float v0 = vb_[(size_t)(s0 + 0) * DD];
      float v1 = vb_[(size_t)(s0 + 1) * DD];
      float v2 = vb_[(size_t)(s0 + 2) * DD];
      float v3 = vb_[(size_t)(s0 + 3) * DD];
      float k0 = kb_[(size_t)(s0 + 0) * DD];
      float k1 = kb_[(size_t)(s0 + 1) * DD];
      float k2 = kb_[(size_t)(s0 + 2) * DD];
      float k3 = kb_[(size_t)(s0 + 3) * DD];
      double w0 = wns[s0 + 0], w1 = wns[s0 + 1], w2 = wns[s0 + 2], w3 = wns[s0 + 3];
      h0 += w0 * (double)v0; h1 += w1 * (double)v1;
      h2 += w2 * (double)v2; h3 += w3 * (double)v3;
      m0 += w0 * (double)k0; m1 += w1 * (double)k1;
      m2 += w2 * (double)k2; m3 += w3 * (double)k3;
    }
    hreg = (h0 + h1) + (h2 + h3);
    mu = (m0 + m1) + (m2 + m3);
  }

  // ---- mu0 = expmap0(clip_tangent(mu)) ----
  double x2c;
  {
    double n2 = blockSum(mu * mu, red, tid);
    double n = sqrt(n2);
    double cf = fmin(4.0 / (n + 1e-8), 1.0);
    double ncl = fmax(n * cf, 1e-15);
    double th = tanh(ncl);
    xc[tid] = mu * (th * cf / ncl);
    x2c = th * th;
  }
  __syncthreads();

  // ---- Karcher flow: 3 Riemannian SGD steps ----
  for (int it = 0; it < 3; ++it) {
    if (tid < SS) {
      double dot;
      SDOT(xc, khT, dot);
      double y2 = y2s[tid];
      double A = 1.0 - 2.0 * dot + y2;
      double Dn = fmax(1.0 - 2.0 * dot + x2c * y2, 1e-15);
      double Bc = 1.0 - x2c;
      double u2 = (A * A * x2c - 2.0 * A * Bc * dot + Bc * Bc * y2) / (Dn * Dn);
      double unr = sqrt(fmax(u2, 0.0));
      double un = fmax(unr, 1e-15);
      double coef = fmax(Bc, 1e-15) * atanh(fmin(un, 1.0 - 1e-7)) / un;
      double cs = wns[tid] * coef / Dn;
      sA[tid] = cs;
      sB[tid] = cs * A;
    }
    double S1 = reduceS_sum(sB, red, tid);   // syncs cover sA/sB writes
    double g;
    DSUM(sA, khB, g);
    double xold = xc[tid];
    double Bc = 1.0 - x2c;
    double vg = Bc * g - S1 * xold;           // v_grad[d]
    double nv2 = blockSum(vg * vg, red, tid);
    double nv = 0.1 * sqrt(nv2);
    double cf = fmin(4.0 / (nv + 1e-8), 1.0);
    double nw = fmax(nv * cf, 1e-15);
    double tsc = tanh(nw / fmax(Bc, 1e-15));
    double zco = tsc * 0.1 * cf / nw;
    double z = zco * vg;
    double xz = blockSum(xold * z, red, tid);
    double z2 = tsc * tsc;
    double den = fmax(1.0 + 2.0 * xz + x2c * z2, 1e-15);
    double xnew = ((1.0 + 2.0 * xz + z2) * xold + (1.0 - x2c) * z) / den;
    xc[tid] = xnew;
    x2c = blockSum(xnew * xnew, red, tid);    // syncs cover xc write
  }

  // ---- k_centroid = projx(mu + noise) ----
  {
    double cn = xc[tid] + noiseval;
    double n2 = blockSum(cn * cn, red, tid);
    double nn = sqrt(n2);
    if (nn > 1.0 - 1e-5) cn *= (1.0 - 1e-5) / fmax(nn, 1e-15);
    xc[tid] = cn;
    x2c = blockSum(cn * cn, red, tid);        // syncs cover xc write
  }

  // ---- c2k distances, entropy, variance; alf/bet for weighted_k ----
  if (tid < SS) {
    double dot;
    SDOT(xc, khT, dot);
    double y2 = y2s[tid];
    double A = 1.0 - 2.0 * dot + y2;
    double Dn = fmax(1.0 - 2.0 * dot + x2c * y2, 1e-15);
    double Bc = 1.0 - x2c;
    double u2 = (A * A * x2c - 2.0 * A * Bc * dot + Bc * Bc * y2) / (Dn * Dn);
    double unr = sqrt(fmax(u2, 0.0));
    double c2k = 2.0 * atanh(fmin(unr, 1.0 - 1e-7));
    sA[tid] = wns[tid] * c2k * c2k;
    sB[tid] = -wns[tid] * log(wns[tid] + 1e-8);
    double un = fmax(unr, 1e-15);
    double gl = fmax(Bc, 1e-15) * atanh(fmin(un, 1.0 - 1e-7)) / (un * Dn);
    double sq = sqrt(wun[tid] + 1e-8);
    alf[tid] = -sq * gl * A;
    bet[tid] = sq * gl * Bc;
  }
  double variance = reduceS_sum(sA, red, tid);
  double entropy = reduceS_sum(sB, red, tid);
  double tau = (double)tau_p[0];
  double tension = variance - tau * exp(entropy);

  // ---- power iteration on weighted_k (rank-structured) ----
  {
    double n2 = blockSum(vrndval * vrndval, red, tid);
    vr[tid] = vrndval / fmax(sqrt(n2), 1e-8);
  }
  for (int it = 0; it < 3; ++it) {
    double dxv = blockSum(xc[tid] * vr[tid], red, tid);  // syncs cover vr write
    if (tid < SS) {
      double dot;
      SDOT(vr, khT, dot);
      double pj = alf[tid] * dxv + bet[tid] * dot;
      sA[tid] = alf[tid] * pj;
      sB[tid] = bet[tid] * pj;
    }
    double T1 = reduceS_sum(sA, red, tid);
    double g;
    DSUM(sB, khB, g);
    double vnew = T1 * xc[tid] + g;
    double n2 = blockSum(vnew * vnew, red, tid);
    vr[tid] = vnew / fmax(sqrt(n2), 1e-8);
  }

  // ---- w_proj ----
  double wproj;
  {
    double wg = vr[tid] / fmax(1.0 - x2c, 1e-15);
    double nq = fmax(sqrt(x2q), 1e-15);
    double aq = atanh(fmin(nq, 1.0 - 1e-7)) / nq;
    double nc = fmax(sqrt(x2c), 1e-15);
    double ac = atanh(fmin(nc, 1.0 - 1e-7)) / nc;
    double f = aq * xq[tid] - ac * xc[tid];
    double n2 = blockSum(f * f, red, tid);
    double fb = f / fmax(sqrt(n2), 1e-8);
    wproj = (variance > 1e-5) ? wg : fb;
  }

  // ---- h_comp, x, pitchfork RK4 ----
  double hn2 = blockSum(hreg * hreg, red, tid);
  double hn = sqrt(hn2);
  double hsc = asinh(hn) / (hn + 1e-8);
  double hc = hsc * hreg;
  double x = blockSum(hc * wproj, red, tid);
  double xi = (x == 0.0) ? odeval : x;
  const double dt = 0.5;
#pragma unroll
  for (int r = 0; r < 4; ++r) {
    double k1 = dt * (tension * xi - xi * xi * xi);
    double a2 = xi + 0.5 * k1;
    double k2 = dt * (tension * a2 - a2 * a2 * a2);
    double a3 = xi + 0.5 * k2;
    double k3 = dt * (tension * a3 - a3 * a3 * a3);
    double a4 = xi + k3;
    double k4 = dt * (tension * a4 - a4 * a4 * a4);
    xi += (k1 + 2.0 * k2 + 2.0 * k3 + k4) / 6.0;
  }
  double ts = (double)ts_p[0];
  double hp = (hc + (xi - x) * wproj) * ts;
  double hp2 = blockSum(hp * hp, red, tid);
  double nhp = sqrt(hp2);
  double cf = fmin(4.0 / (nhp + 1e-8), 1.0);
  double ncl = fmax(nhp * cf, 1e-15);
  double th = tanh(ncl);
  double nb = fmax(th, 1e-15);
  double ab = atanh(fmin(nb, 1.0 - 1e-7)) / nb;
  double hob = ab * th * cf / ncl * hp;
  double gate = fmax(tanh(tension / fmax(tau, 1e-3)), 0.0);

  // ---- fused output GEMM: out[row] = h_fused . Wo^T + bo (r4 gemm_out pattern) ----
  hfl[tid] = (float)((1.0 - gate) * hreg + gate * hob);
  __syncthreads();
  double o = colDot(hfl, WoT, tid) + (double)bo[tid];
  out[rowOff + tid] = (float)o;
}

// ---------------- launch ----------------
extern "C" void kernel_launch(void* const* d_in, const int* in_sizes, int n_in,
                              void* d_out, int out_size, void* d_ws, size_t ws_size,
                              hipStream_t stream) {
  const float* q_in = (const float*)d_in[0];
  const float* k_in = (const float*)d_in[1];
  const float* v_in = (const float*)d_in[2];
  const float* Wq = (const float*)d_in[3];
  const float* bq = (const float*)d_in[4];
  const float* Wk = (const float*)d_in[5];
  const float* bk = (const float*)d_in[6];
  const float* Wv = (const float*)d_in[7];
  const float* bv = (const float*)d_in[8];
  const float* Wo = (const float*)d_in[9];
  const float* bo = (const float*)d_in[10];
  const float* tau = (const float*)d_in[11];
  const float* ts = (const float*)d_in[12];
  float* out = (float*)d_out;
  (void)in_sizes; (void)n_in; (void)out_size; (void)ws_size;

  char* base = (char*)d_ws;
  size_t off = 0;
  auto alloc = [&](size_t bytes) -> void* {
    void* p = base + off;
    off += (bytes + 255) & ~(size_t)255;
    return p;
  };
  float* WqT = (float*)alloc((size_t)DD * DD * 4);
  float* WkT = (float*)alloc((size_t)DD * DD * 4);
  float* WvT = (float*)alloc((size_t)DD * DD * 4);
  float* WoT = (float*)alloc((size_t)DD * DD * 4);
  float* kb = (float*)alloc((size_t)NE * 4);
  float* vb = (float*)alloc((size_t)NE * 4);
  float* qh = (float*)alloc((size_t)NE * 4);
  float* kh = (float*)alloc((size_t)NE * 4);
  float* khT = (float*)alloc((size_t)NE * 4);
  double* y2g = (double*)alloc((size_t)NROW * 8);

  hipLaunchKernelGGL(transpose4, dim3(4 * DD), dim3(DD), 0, stream,
                     Wq, Wk, Wv, Wo, WqT, WkT, WvT, WoT);
  hipLaunchKernelGGL(proj_kernel, dim3(NROW, 3), dim3(DD), 0, stream,
                     q_in, k_in, v_in, WqT, WkT, WvT, bq, bk, bv,
                     qh, kb, vb, kh, khT, y2g);
  hipLaunchKernelGGL(resonance_main, dim3(NROW), dim3(DD), 0, stream,
                     qh, kh, khT, kb, vb, y2g, WoT, bo, tau, ts, out);
}